// Round 6
// baseline (994.071 us; speedup 1.0000x reference)
//
#include <hip/hip_runtime.h>
#include <math.h>

#define N_NODES 100000
#define N_EDGES 1600000
#define IN_F 64
#define OUT_F 64
#define N_COEF 8
#define KTOT 1152          // 2 paths * 64 in-feats * 9 (1 silu + 8 bases)
#define NT 128             // nodes per block in kan kernel
#define KC 72              // K-chunk = 8 in-feat groups of 9

#define DEG_PAD 100096     // deg region, floats
#define WC_ELEMS (KTOT * OUT_F)      // 73728 floats
#define AGG_ELEMS (N_NODES * IN_F)   // 6,400,000 floats

// knot: g(t) = (t-3)*0.4 - 1, t = 0..11
__device__ __forceinline__ float gknot(int t) {
    return (float)(t - 3) * 0.4f + (-1.0f);
}

// Cox-de Boor exactly as reference: 11 degree-0 indicators -> 8 cubic bases
__device__ __forceinline__ void spline_bases(float v, float* out8) {
    float b[11];
#pragma unroll
    for (int t = 0; t < 11; ++t) {
        b[t] = (v >= gknot(t) && v < gknot(t + 1)) ? 1.0f : 0.0f;
    }
#pragma unroll
    for (int j = 1; j <= 3; ++j) {
#pragma unroll
        for (int t = 0; t < 11 - j; ++t) {
            float gl  = gknot(t);
            float gr  = gknot(t + j);
            float gl1 = gknot(t + 1);
            float gr1 = gknot(t + j + 1);
            float left  = (v - gl) / (gr - gl);
            float right = (gr1 - v) / (gr1 - gl1);
            b[t] = left * b[t] + right * b[t + 1];
        }
    }
#pragma unroll
    for (int c = 0; c < 8; ++c) out8[c] = b[c];
}

__global__ void deg_kernel(const int* __restrict__ ei, float* __restrict__ deg) {
    int e = blockIdx.x * blockDim.x + threadIdx.x;
    if (e < N_EDGES) atomicAdd(&deg[ei[N_EDGES + e]], 1.0f);
}

__global__ void dinv_kernel(float* __restrict__ deg) {
    int n = blockIdx.x * blockDim.x + threadIdx.x;
    if (n < N_NODES) {
        float d = deg[n];
        deg[n] = (d > 0.0f) ? rsqrtf(d) : 0.0f;   // d>0 implies d>=1, max(d,1)=d
    }
}

// one wave (64 lanes) per edge: lanes = features
__global__ void scatter_kernel(const float* __restrict__ x, const int* __restrict__ ei,
                               const float* __restrict__ dinv, float* __restrict__ agg) {
    long long gtid = (long long)blockIdx.x * blockDim.x + threadIdx.x;
    int wid = (int)(gtid >> 6);
    int lane = threadIdx.x & 63;
    if (wid >= N_EDGES) return;
    int s = ei[wid];
    int d = ei[N_EDGES + wid];
    float c = dinv[s] * dinv[d];
    atomicAdd(&agg[(long long)d * 64 + lane], x[(long long)s * 64 + lane] * c);
}

// Build combined transposed weight Wc[k][o], k = p*576 + i*9 + c
//   c==0 -> base_w_p[o][i] (silu path), c in 1..8 -> spline_w_p[o][i][c-1]
__global__ void wprep_kernel(const float* __restrict__ bwl, const float* __restrict__ swl,
                             const float* __restrict__ bwc, const float* __restrict__ swc,
                             float* __restrict__ Wc) {
    int gid = blockIdx.x * blockDim.x + threadIdx.x;
    if (gid >= KTOT * OUT_F) return;
    int o = gid & 63;
    int k = gid >> 6;
    int p = k / 576;
    int rem = k - p * 576;
    int i = rem / 9;
    int c = rem - i * 9;
    const float* bw = p ? bwc : bwl;
    const float* sw = p ? swc : swl;
    float v = (c == 0) ? bw[o * IN_F + i] : sw[o * (IN_F * N_COEF) + i * N_COEF + (c - 1)];
    Wc[k * OUT_F + o] = v;
}

// out[n][o] = sum_k feat[n][k] * Wc[k][o]; feat computed on the fly per K-chunk.
// 256 threads: og = tid&7 (8 outs each), ng = tid>>3 (4 nodes each) -> 128 nodes/block.
// NOTE: safe even if agg aliases out — all agg reads in a block precede all out
// writes (epilogue), and blocks own disjoint 128-node row ranges.
__global__ __launch_bounds__(256, 2)
void kan_kernel(const float* __restrict__ x, const float* __restrict__ agg,
                const float* __restrict__ Wc, float* __restrict__ out) {
    __shared__ float sfeat[KC][NT];     // 36864 B
    __shared__ float sw[KC][OUT_F];     // 18432 B
    int tid = threadIdx.x;
    int nbase = blockIdx.x * NT;
    int og = tid & 7;
    int ng = tid >> 3;
    int o0 = og * 8;
    int n0 = ng * 4;

    float acc[4][8];
#pragma unroll
    for (int a = 0; a < 4; ++a)
#pragma unroll
        for (int b = 0; b < 8; ++b) acc[a][b] = 0.0f;

    for (int ch = 0; ch < 16; ++ch) {
        int p = ch >> 3;
        int i0 = (ch & 7) * 8;
        const float* src = p ? agg : x;

        // stage weights (rows ch*KC .. ch*KC+71), coalesced
        float* swl_flat = &sw[0][0];
        for (int r = tid; r < KC * OUT_F; r += 256) {
            swl_flat[r] = Wc[ch * KC * OUT_F + r];
        }

        // compute features: 8 in-feat groups x 128 nodes = 1024 tasks, 4 per thread
#pragma unroll
        for (int rr = 0; rr < 4; ++rr) {
            int t = tid + 256 * rr;
            int nl = t & (NT - 1);
            int g = t >> 7;
            int node = nbase + nl;
            float v = (node < N_NODES) ? src[(long long)node * 64 + (i0 + g)] : 0.0f;
            float sig = 1.0f / (1.0f + expf(-v));
            sfeat[g * 9 + 0][nl] = v * sig;
            float bs[8];
            spline_bases(v, bs);
#pragma unroll
            for (int c = 0; c < 8; ++c) sfeat[g * 9 + 1 + c][nl] = bs[c];
        }
        __syncthreads();

#pragma unroll 4
        for (int k = 0; k < KC; ++k) {
            const float4 f  = *(const float4*)(&sfeat[k][n0]);
            const float4 wa = *(const float4*)(&sw[k][o0]);
            const float4 wb = *(const float4*)(&sw[k][o0 + 4]);
            const float fv[4] = {f.x, f.y, f.z, f.w};
            const float wv[8] = {wa.x, wa.y, wa.z, wa.w, wb.x, wb.y, wb.z, wb.w};
#pragma unroll
            for (int a = 0; a < 4; ++a)
#pragma unroll
                for (int b = 0; b < 8; ++b)
                    acc[a][b] = fmaf(fv[a], wv[b], acc[a][b]);
        }
        __syncthreads();
    }

#pragma unroll
    for (int nn = 0; nn < 4; ++nn) {
        int node = nbase + n0 + nn;
        if (node < N_NODES) {
            float4 v0 = make_float4(acc[nn][0], acc[nn][1], acc[nn][2], acc[nn][3]);
            float4 v1 = make_float4(acc[nn][4], acc[nn][5], acc[nn][6], acc[nn][7]);
            *(float4*)(&out[(long long)node * 64 + o0])     = v0;
            *(float4*)(&out[(long long)node * 64 + o0 + 4]) = v1;
        }
    }
}

extern "C" void kernel_launch(void* const* d_in, const int* in_sizes, int n_in,
                              void* d_out, int out_size, void* d_ws, size_t ws_size,
                              hipStream_t stream) {
    const float* x   = (const float*)d_in[0];
    const float* bwl = (const float*)d_in[1];
    const float* swl = (const float*)d_in[2];
    const float* bwc = (const float*)d_in[3];
    const float* swc = (const float*)d_in[4];
    const int*   ei  = (const int*)d_in[5];
    float* out = (float*)d_out;

    float* ws  = (float*)d_ws;
    float* deg = ws;                          // DEG_PAD floats
    float* Wc  = ws + DEG_PAD;                // WC_ELEMS floats
    const size_t base_elems = DEG_PAD + WC_ELEMS;           // 173,824
    const size_t need_big   = (base_elems + (size_t)AGG_ELEMS) * sizeof(float);

    // agg placement: in ws if it fits, else alias onto d_out (safe — see kan_kernel note)
    float* agg = (ws_size >= need_big) ? (ws + base_elems) : out;

    // zero deg every launch; zero agg every launch (harness poisons, never re-zeros)
    hipMemsetAsync(deg, 0, (size_t)DEG_PAD * sizeof(float), stream);
    hipMemsetAsync(agg, 0, (size_t)AGG_ELEMS * sizeof(float), stream);

    deg_kernel<<<(N_EDGES + 255) / 256, 256, 0, stream>>>(ei, deg);
    dinv_kernel<<<(N_NODES + 255) / 256, 256, 0, stream>>>(deg);

    long long scatter_threads = (long long)N_EDGES * 64;
    int scatter_blocks = (int)((scatter_threads + 255) / 256);
    scatter_kernel<<<scatter_blocks, 256, 0, stream>>>(x, ei, deg, agg);

    wprep_kernel<<<(KTOT * OUT_F + 255) / 256, 256, 0, stream>>>(bwl, swl, bwc, swc, Wc);

    kan_kernel<<<(N_NODES + NT - 1) / NT, 256, 0, stream>>>(x, agg, Wc, out);
}

// Round 7
// 698.671 us; speedup vs baseline: 1.4228x; 1.4228x over previous
//
#include <hip/hip_runtime.h>
#include <math.h>

#define N_NODES 100000
#define N_EDGES 1600000
#define IN_F 64
#define OUT_F 64

// K layout for the fused KAN GEMM:
//   original k = path*576 + i*9 + c   (c=0: silu, c=1..8: spline bases), K=1152
//   hi/lo split k' = 2k{+1},          K'=2304
//   chunk = 288 k' (16 in-feats), 8 chunks (4 per path), 9 MFMA K-steps of 32 per chunk
#define KCH 288
#define AST 296            // LDS row stride in bf16 elems (592 B, 16B-aligned rows)

#define DEG_PAD 100096                  // deg region, floats
#define WT_U16 (OUT_F * 1152)           // 73728 bf16 weights
#define BASE_ELEMS (DEG_PAD + WT_U16/2) // 136960 f32 slots
#define AGG_ELEMS (N_NODES * IN_F)      // 6,400,000 floats

typedef __attribute__((ext_vector_type(8))) short bf16x8;
typedef __attribute__((ext_vector_type(4))) float f32x4;

__device__ __forceinline__ unsigned int bf16_rne(float v) {
    unsigned int u = __float_as_uint(v);
    u += 0x7FFFu + ((u >> 16) & 1u);
    return u >> 16;
}

// pack f as hi(trunc-bf16) + lo(trunc-bf16 of residual): hi | lo<<16
__device__ __forceinline__ unsigned int pack_hilo(float f) {
    unsigned int u = __float_as_uint(f);
    float hi_f = __uint_as_float(u & 0xFFFF0000u);
    float lo_f = f - hi_f;
    unsigned int lo = __float_as_uint(lo_f) >> 16;
    return (u >> 16) | (lo << 16);
}

// 8 cubic B-spline bases, Cox-de Boor with constant reciprocals (knots 0.4t-2.2)
__device__ __forceinline__ void spline_bases(float v, float* out8) {
    float b[11];
#pragma unroll
    for (int t = 0; t < 11; ++t) {
        float gl = 0.4f * t - 2.2f;
        b[t] = (v >= gl && v < gl + 0.4f) ? 1.0f : 0.0f;
    }
#pragma unroll
    for (int j = 1; j <= 3; ++j) {
        const float inv = (j == 1) ? 2.5f : (j == 2) ? 1.25f : (2.5f / 3.0f);
#pragma unroll
        for (int t = 0; t < 11 - j; ++t) {
            float gl  = 0.4f * t - 2.2f;
            float gr1 = 0.4f * (t + j + 1) - 2.2f;
            b[t] = (v - gl) * inv * b[t] + (gr1 - v) * inv * b[t + 1];
        }
    }
#pragma unroll
    for (int c = 0; c < 8; ++c) out8[c] = b[c];
}

__global__ void deg_kernel(const int* __restrict__ ei, float* __restrict__ deg) {
    int e = blockIdx.x * blockDim.x + threadIdx.x;
    if (e < N_EDGES) atomicAdd(&deg[ei[N_EDGES + e]], 1.0f);
}

__global__ void dinv_kernel(float* __restrict__ deg) {
    int n = blockIdx.x * blockDim.x + threadIdx.x;
    if (n < N_NODES) {
        float d = deg[n];
        deg[n] = (d > 0.0f) ? rsqrtf(d) : 0.0f;
    }
}

// one wave per edge: lanes = features
__global__ void scatter_kernel(const float* __restrict__ x, const int* __restrict__ ei,
                               const float* __restrict__ dinv, float* __restrict__ agg) {
    long long gtid = (long long)blockIdx.x * blockDim.x + threadIdx.x;
    int wid = (int)(gtid >> 6);
    int lane = threadIdx.x & 63;
    if (wid >= N_EDGES) return;
    int s = ei[wid];
    int d = ei[N_EDGES + wid];
    float c = dinv[s] * dinv[d];
    atomicAdd(&agg[d * 64 + lane], x[s * 64 + lane] * c);
}

// Wt[o][k] bf16, k = p*576 + i*9 + c
__global__ void wprep_kernel(const float* __restrict__ bwl, const float* __restrict__ swl,
                             const float* __restrict__ bwc, const float* __restrict__ swc,
                             unsigned short* __restrict__ Wt) {
    int gid = blockIdx.x * blockDim.x + threadIdx.x;
    if (gid >= OUT_F * 1152) return;
    int o = gid / 1152;
    int k = gid - o * 1152;
    int p = k / 576;
    int rem = k - p * 576;
    int i = rem / 9;
    int c = rem - i * 9;
    const float* bw = p ? bwc : bwl;
    const float* sw = p ? swc : swl;
    float v = (c == 0) ? bw[o * IN_F + i] : sw[o * 512 + i * 8 + (c - 1)];
    Wt[gid] = (unsigned short)bf16_rne(v);
}

// MFMA KAN: 64 nodes/block, 4 waves, wave -> 16 nodes x 64 outs.
// A (features, hi/lo bf16) and W (bf16, duplicated per hi/lo slot) staged in LDS.
// Safe if agg aliases out: all agg reads (chunks 4..7) precede epilogue out writes,
// and blocks own disjoint 64-node row ranges.
__global__ __launch_bounds__(256, 2)
void kan_mfma_kernel(const float* __restrict__ x, const float* __restrict__ agg,
                     const unsigned short* __restrict__ Wt, float* __restrict__ out) {
    __shared__ __align__(16) unsigned short A_lds[64 * AST];  // 37888 B
    __shared__ __align__(16) unsigned short W_lds[64 * AST];  // 37888 B

    int tid = threadIdx.x;
    int nbase = blockIdx.x * 64;
    int wid = tid >> 6;
    int lane = tid & 63;

    f32x4 acc[4];
#pragma unroll
    for (int t = 0; t < 4; ++t) acc[t] = (f32x4){0.f, 0.f, 0.f, 0.f};

    for (int chunk = 0; chunk < 8; ++chunk) {
        int path = chunk >> 2;
        int i0 = (chunk & 3) * 16;
        const float* src = path ? agg : x;

        // ---- stage weights: W_lds[o][kk'] = Wt[o][chunk*144 + kk'/2]
        for (int f = tid; f < 64 * KCH; f += 256) {
            int o = f / KCH;
            int kk = f - o * KCH;
            W_lds[o * AST + kk] = Wt[o * 1152 + chunk * 144 + (kk >> 1)];
        }

        // ---- compute features: node = tid&63, grp = tid>>6 covers 4 in-feats
        {
            int n = tid & 63;
            int grp = tid >> 6;
            int node = nbase + n;
            float4 v4 = make_float4(0.f, 0.f, 0.f, 0.f);
            if (node < N_NODES) v4 = *(const float4*)&src[node * 64 + i0 + grp * 4];
            float vv[4] = {v4.x, v4.y, v4.z, v4.w};
            unsigned int* Arow_base = (unsigned int*)&A_lds[n * AST];
#pragma unroll
            for (int jj = 0; jj < 4; ++jj) {
                int iL = grp * 4 + jj;
                float v = vv[jj];
                unsigned int* Au = Arow_base + iL * 9;   // 9 uints = 18 bf16 slots
                float sig = __builtin_amdgcn_rcpf(1.0f + __expf(-v));
                Au[0] = pack_hilo(v * sig);
                float bs[8];
                spline_bases(v, bs);
#pragma unroll
                for (int c = 0; c < 8; ++c) Au[1 + c] = pack_hilo(bs[c]);
            }
        }
        __syncthreads();

        // ---- MFMA over 9 K-steps of 32
        {
            int arow = (wid << 4) + (lane & 15);
            int kfrag = (lane >> 4) * 8;
            const unsigned short* Abase = &A_lds[arow * AST + kfrag];
            int bcol = lane & 15;
#pragma unroll
            for (int s = 0; s < 9; ++s) {
                bf16x8 a = *(const bf16x8*)(Abase + s * 32);
#pragma unroll
                for (int t = 0; t < 4; ++t) {
                    bf16x8 b = *(const bf16x8*)(&W_lds[(t * 16 + bcol) * AST + kfrag + s * 32]);
                    acc[t] = __builtin_amdgcn_mfma_f32_16x16x32_bf16(a, b, acc[t], 0, 0, 0);
                }
            }
        }
        __syncthreads();
    }

    // ---- epilogue: C/D layout col=lane&15, row=(lane>>4)*4+reg
    int orow0 = (lane >> 4) * 2;  // placeholder, corrected below
    (void)orow0;
#pragma unroll
    for (int t = 0; t < 4; ++t) {
#pragma unroll
        for (int r = 0; r < 4; ++r) {
            int node = nbase + (wid << 4) + (lane >> 4) * 4 + r;
            if (node < N_NODES) out[node * 64 + t * 16 + (lane & 15)] = acc[t][r];
        }
    }
}

extern "C" void kernel_launch(void* const* d_in, const int* in_sizes, int n_in,
                              void* d_out, int out_size, void* d_ws, size_t ws_size,
                              hipStream_t stream) {
    const float* x   = (const float*)d_in[0];
    const float* bwl = (const float*)d_in[1];
    const float* swl = (const float*)d_in[2];
    const float* bwc = (const float*)d_in[3];
    const float* swc = (const float*)d_in[4];
    const int*   ei  = (const int*)d_in[5];
    float* out = (float*)d_out;

    float* ws  = (float*)d_ws;
    float* deg = ws;
    unsigned short* Wt = (unsigned short*)(ws + DEG_PAD);
    const size_t need_big = (BASE_ELEMS + (size_t)AGG_ELEMS) * sizeof(float);

    // agg: in ws if it fits, else alias onto d_out (safe — see kan_mfma_kernel note)
    float* agg = (ws_size >= need_big) ? (ws + BASE_ELEMS) : out;

    hipMemsetAsync(deg, 0, (size_t)DEG_PAD * sizeof(float), stream);
    hipMemsetAsync(agg, 0, (size_t)AGG_ELEMS * sizeof(float), stream);

    deg_kernel<<<(N_EDGES + 255) / 256, 256, 0, stream>>>(ei, deg);
    dinv_kernel<<<(N_NODES + 255) / 256, 256, 0, stream>>>(deg);

    long long scatter_threads = (long long)N_EDGES * 64;
    int scatter_blocks = (int)((scatter_threads + 255) / 256);
    scatter_kernel<<<scatter_blocks, 256, 0, stream>>>(x, ei, deg, agg);

    wprep_kernel<<<(OUT_F * 1152 + 255) / 256, 256, 0, stream>>>(bwl, swl, bwc, swc, Wt);

    kan_mfma_kernel<<<(N_NODES + 63) / 64, 256, 0, stream>>>(x, agg, Wt, out);
}

// Round 8
// 542.149 us; speedup vs baseline: 1.8336x; 1.2887x over previous
//
#include <hip/hip_runtime.h>
#include <math.h>

#define N_NODES 100000
#define N_EDGES 1600000
#define IN_F 64
#define OUT_F 64

// KAN GEMM K layout: k = path*576 + i*9 + c (c=0 silu, 1..8 bases), K=1152
// hi/lo split k' = 2k{+1}, K'=2304; chunk = 288 k' (16 in-feats), 8 chunks
#define KCH 288
#define AST 296            // LDS row stride in bf16 elems

#define DEG_PAD 100352                  // deg region, floats (98*1024)
#define WT_SLOTS 36864                  // 73728 bf16 weights = 36864 f32 slots
#define ROWPTR_SLOTS 100352
#define SUMS_SLOTS 128
#define CSR_SLOTS N_EDGES
#define AGG_ELEMS (N_NODES * IN_F)      // 6,400,000 floats

typedef __attribute__((ext_vector_type(8))) short bf16x8;
typedef __attribute__((ext_vector_type(4))) float f32x4;

__device__ __forceinline__ unsigned int bf16_rne(float v) {
    unsigned int u = __float_as_uint(v);
    u += 0x7FFFu + ((u >> 16) & 1u);
    return u >> 16;
}

// pack f as hi(trunc-bf16) + lo(trunc-bf16 of residual): hi | lo<<16
__device__ __forceinline__ unsigned int pack_hilo(float f) {
    unsigned int u = __float_as_uint(f);
    float hi_f = __uint_as_float(u & 0xFFFF0000u);
    float lo_f = f - hi_f;
    unsigned int lo = __float_as_uint(lo_f) >> 16;
    return (u >> 16) | (lo << 16);
}

// 8 cubic B-spline bases, Cox-de Boor with constant reciprocals (knots 0.4t-2.2)
__device__ __forceinline__ void spline_bases(float v, float* out8) {
    float b[11];
#pragma unroll
    for (int t = 0; t < 11; ++t) {
        float gl = 0.4f * t - 2.2f;
        b[t] = (v >= gl && v < gl + 0.4f) ? 1.0f : 0.0f;
    }
#pragma unroll
    for (int j = 1; j <= 3; ++j) {
        const float inv = (j == 1) ? 2.5f : (j == 2) ? 1.25f : (2.5f / 3.0f);
#pragma unroll
        for (int t = 0; t < 11 - j; ++t) {
            float gl  = 0.4f * t - 2.2f;
            float gr1 = 0.4f * (t + j + 1) - 2.2f;
            b[t] = (v - gl) * inv * b[t] + (gr1 - v) * inv * b[t + 1];
        }
    }
#pragma unroll
    for (int c = 0; c < 8; ++c) out8[c] = b[c];
}

__global__ void deg_kernel(const int* __restrict__ ei, float* __restrict__ deg) {
    int e = blockIdx.x * blockDim.x + threadIdx.x;
    if (e < N_EDGES) atomicAdd(&deg[ei[N_EDGES + e]], 1.0f);
}

__global__ void dinv_kernel(float* __restrict__ deg) {
    int n = blockIdx.x * blockDim.x + threadIdx.x;
    if (n < N_NODES) {
        float d = deg[n];
        deg[n] = (d > 0.0f) ? rsqrtf(d) : 0.0f;
    }
}

// ---- 3-kernel exclusive scan of deg (float counts) -> rowptr (int) ----
__global__ void scan_part(const float* __restrict__ deg, int* __restrict__ rowptr,
                          int* __restrict__ bsums) {
    __shared__ int tmp[1024];
    int t = threadIdx.x;
    int gi = blockIdx.x * 1024 + t;
    int v = (int)deg[gi];
    tmp[t] = v;
    __syncthreads();
    for (int off = 1; off < 1024; off <<= 1) {
        int add = (t >= off) ? tmp[t - off] : 0;
        __syncthreads();
        tmp[t] += add;
        __syncthreads();
    }
    rowptr[gi] = tmp[t] - v;                 // exclusive
    if (t == 1023) bsums[blockIdx.x] = tmp[t];
}

__global__ void scan_sums(int* __restrict__ bsums) {
    __shared__ int tmp[128];
    int t = threadIdx.x;
    int v = (t < DEG_PAD / 1024) ? bsums[t] : 0;
    tmp[t] = v;
    __syncthreads();
    for (int off = 1; off < 128; off <<= 1) {
        int add = (t >= off) ? tmp[t - off] : 0;
        __syncthreads();
        tmp[t] += add;
        __syncthreads();
    }
    if (t < DEG_PAD / 1024) bsums[t] = tmp[t] - v;   // exclusive
}

__global__ void scan_add(int* __restrict__ rowptr, const int* __restrict__ bsums) {
    int gi = blockIdx.x * 1024 + threadIdx.x;
    rowptr[gi] += bsums[blockIdx.x];
}

// fill CSR: rowptr drifts start->end; csr_src[pos] = src
__global__ void fill_kernel(const int* __restrict__ ei, int* __restrict__ rowptr,
                            int* __restrict__ csr) {
    int e = blockIdx.x * blockDim.x + threadIdx.x;
    if (e >= N_EDGES) return;
    int s = ei[e];
    int d = ei[N_EDGES + e];
    int pos = atomicAdd(&rowptr[d], 1);
    csr[pos] = s;
}

// gather: one wave per dst node, lane = feature; agg[d] = dinv[d] * sum dinv[s]*x[s]
__global__ __launch_bounds__(256)
void gather_kernel(const float* __restrict__ x, const int* __restrict__ csr,
                   const int* __restrict__ rowptr, const float* __restrict__ dinv,
                   float* __restrict__ agg) {
    int wid = (int)((blockIdx.x * 256 + threadIdx.x) >> 6);
    int lane = threadIdx.x & 63;
    if (wid >= N_NODES) return;
    int end = rowptr[wid];                       // post-fill = bucket end
    int start = (wid == 0) ? 0 : rowptr[wid - 1];
    float acc = 0.0f;
    int j = start;
    for (; j + 3 < end; j += 4) {
        int s0 = csr[j], s1 = csr[j + 1], s2 = csr[j + 2], s3 = csr[j + 3];
        float a0 = x[s0 * 64 + lane] * dinv[s0];
        float a1 = x[s1 * 64 + lane] * dinv[s1];
        float a2 = x[s2 * 64 + lane] * dinv[s2];
        float a3 = x[s3 * 64 + lane] * dinv[s3];
        acc += a0 + a1 + a2 + a3;
    }
    for (; j < end; ++j) {
        int s = csr[j];
        acc += x[s * 64 + lane] * dinv[s];
    }
    agg[wid * 64 + lane] = acc * dinv[wid];
}

// fallback: one wave per edge, f32 atomics (used only if ws too small for CSR)
__global__ void scatter_kernel(const float* __restrict__ x, const int* __restrict__ ei,
                               const float* __restrict__ dinv, float* __restrict__ agg) {
    long long gtid = (long long)blockIdx.x * blockDim.x + threadIdx.x;
    int wid = (int)(gtid >> 6);
    int lane = threadIdx.x & 63;
    if (wid >= N_EDGES) return;
    int s = ei[wid];
    int d = ei[N_EDGES + wid];
    float c = dinv[s] * dinv[d];
    atomicAdd(&agg[d * 64 + lane], x[s * 64 + lane] * c);
}

// Wt[o][k] bf16, k = p*576 + i*9 + c
__global__ void wprep_kernel(const float* __restrict__ bwl, const float* __restrict__ swl,
                             const float* __restrict__ bwc, const float* __restrict__ swc,
                             unsigned short* __restrict__ Wt) {
    int gid = blockIdx.x * blockDim.x + threadIdx.x;
    if (gid >= OUT_F * 1152) return;
    int o = gid / 1152;
    int k = gid - o * 1152;
    int p = k / 576;
    int rem = k - p * 576;
    int i = rem / 9;
    int c = rem - i * 9;
    const float* bw = p ? bwc : bwl;
    const float* sw = p ? swc : swl;
    float v = (c == 0) ? bw[o * IN_F + i] : sw[o * 512 + i * 8 + (c - 1)];
    Wt[gid] = (unsigned short)bf16_rne(v);
}

// MFMA KAN: 64 nodes/block, 4 waves, wave -> 16 nodes x 64 outs.
// Safe if agg aliases out: all agg reads (chunks 4..7) precede epilogue out writes,
// and blocks own disjoint 64-node row ranges.
__global__ __launch_bounds__(256, 2)
void kan_mfma_kernel(const float* __restrict__ x, const float* __restrict__ agg,
                     const unsigned short* __restrict__ Wt, float* __restrict__ out) {
    __shared__ __align__(16) unsigned short A_lds[64 * AST];  // 37888 B
    __shared__ __align__(16) unsigned short W_lds[64 * AST];  // 37888 B

    int tid = threadIdx.x;
    int nbase = blockIdx.x * 64;
    int wid = tid >> 6;
    int lane = tid & 63;

    f32x4 acc[4];
#pragma unroll
    for (int t = 0; t < 4; ++t) acc[t] = (f32x4){0.f, 0.f, 0.f, 0.f};

    for (int chunk = 0; chunk < 8; ++chunk) {
        int path = chunk >> 2;
        int i0 = (chunk & 3) * 16;
        const float* src = path ? agg : x;

        // ---- stage weights: W_lds[o][kk'] = Wt[o][chunk*144 + kk'/2]
        for (int f = tid; f < 64 * KCH; f += 256) {
            int o = f / KCH;
            int kk = f - o * KCH;
            W_lds[o * AST + kk] = Wt[o * 1152 + chunk * 144 + (kk >> 1)];
        }

        // ---- compute features: node = tid&63, grp = tid>>6 covers 4 in-feats
        {
            int n = tid & 63;
            int grp = tid >> 6;
            int node = nbase + n;
            float4 v4 = make_float4(0.f, 0.f, 0.f, 0.f);
            if (node < N_NODES) v4 = *(const float4*)&src[node * 64 + i0 + grp * 4];
            float vv[4] = {v4.x, v4.y, v4.z, v4.w};
            unsigned int* Arow_base = (unsigned int*)&A_lds[n * AST];
#pragma unroll
            for (int jj = 0; jj < 4; ++jj) {
                int iL = grp * 4 + jj;
                float v = vv[jj];
                unsigned int* Au = Arow_base + iL * 9;   // 9 uints = 18 bf16 slots
                float sig = __builtin_amdgcn_rcpf(1.0f + __expf(-v));
                Au[0] = pack_hilo(v * sig);
                float bs[8];
                spline_bases(v, bs);
#pragma unroll
                for (int c = 0; c < 8; ++c) Au[1 + c] = pack_hilo(bs[c]);
            }
        }
        __syncthreads();

        // ---- MFMA over 9 K-steps of 32
        {
            int arow = (wid << 4) + (lane & 15);
            int kfrag = (lane >> 4) * 8;
            const unsigned short* Abase = &A_lds[arow * AST + kfrag];
            int bcol = lane & 15;
#pragma unroll
            for (int s = 0; s < 9; ++s) {
                bf16x8 a = *(const bf16x8*)(Abase + s * 32);
#pragma unroll
                for (int t = 0; t < 4; ++t) {
                    bf16x8 b = *(const bf16x8*)(&W_lds[(t * 16 + bcol) * AST + kfrag + s * 32]);
                    acc[t] = __builtin_amdgcn_mfma_f32_16x16x32_bf16(a, b, acc[t], 0, 0, 0);
                }
            }
        }
        __syncthreads();
    }

    // ---- epilogue: C/D layout col=lane&15, row=(lane>>4)*4+reg
#pragma unroll
    for (int t = 0; t < 4; ++t) {
#pragma unroll
        for (int r = 0; r < 4; ++r) {
            int node = nbase + (wid << 4) + (lane >> 4) * 4 + r;
            if (node < N_NODES) out[node * 64 + t * 16 + (lane & 15)] = acc[t][r];
        }
    }
}

extern "C" void kernel_launch(void* const* d_in, const int* in_sizes, int n_in,
                              void* d_out, int out_size, void* d_ws, size_t ws_size,
                              hipStream_t stream) {
    const float* x   = (const float*)d_in[0];
    const float* bwl = (const float*)d_in[1];
    const float* swl = (const float*)d_in[2];
    const float* bwc = (const float*)d_in[3];
    const float* swc = (const float*)d_in[4];
    const int*   ei  = (const int*)d_in[5];
    float* out = (float*)d_out;

    float* ws  = (float*)d_ws;
    float* deg = ws;                                          // DEG_PAD
    unsigned short* Wt = (unsigned short*)(ws + DEG_PAD);     // WT_SLOTS f32 slots
    int* rowptr = (int*)(ws + DEG_PAD + WT_SLOTS);            // ROWPTR_SLOTS
    int* bsums  = rowptr + ROWPTR_SLOTS;                      // SUMS_SLOTS
    int* csr    = bsums + SUMS_SLOTS;                         // CSR_SLOTS

    const size_t csr_end = (size_t)DEG_PAD + WT_SLOTS + ROWPTR_SLOTS + SUMS_SLOTS + CSR_SLOTS;
    const bool has_csr   = ws_size >= csr_end * sizeof(float);
    const size_t small_end = (size_t)DEG_PAD + WT_SLOTS;
    const size_t agg_base  = has_csr ? csr_end : small_end;
    const bool agg_in_ws   = ws_size >= (agg_base + (size_t)AGG_ELEMS) * sizeof(float);
    float* agg = agg_in_ws ? (ws + agg_base) : out;

    hipMemsetAsync(deg, 0, (size_t)DEG_PAD * sizeof(float), stream);

    deg_kernel<<<(N_EDGES + 255) / 256, 256, 0, stream>>>(ei, deg);

    if (has_csr) {
        scan_part<<<DEG_PAD / 1024, 1024, 0, stream>>>(deg, rowptr, bsums);
        scan_sums<<<1, 128, 0, stream>>>(bsums);
        scan_add<<<DEG_PAD / 1024, 1024, 0, stream>>>(rowptr, bsums);
        dinv_kernel<<<(N_NODES + 255) / 256, 256, 0, stream>>>(deg);
        fill_kernel<<<(N_EDGES + 255) / 256, 256, 0, stream>>>(ei, rowptr, csr);
        gather_kernel<<<(N_NODES * 64 + 255) / 256, 256, 0, stream>>>(x, csr, rowptr, deg, agg);
    } else {
        dinv_kernel<<<(N_NODES + 255) / 256, 256, 0, stream>>>(deg);
        hipMemsetAsync(agg, 0, (size_t)AGG_ELEMS * sizeof(float), stream);
        long long scatter_threads = (long long)N_EDGES * 64;
        int scatter_blocks = (int)((scatter_threads + 255) / 256);
        scatter_kernel<<<scatter_blocks, 256, 0, stream>>>(x, ei, deg, agg);
    }

    wprep_kernel<<<(OUT_F * 1152 + 255) / 256, 256, 0, stream>>>(bwl, swl, bwc, swc, Wt);

    kan_mfma_kernel<<<(N_NODES + 63) / 64, 256, 0, stream>>>(x, agg, Wt, out);
}

// Round 10
// 383.424 us; speedup vs baseline: 2.5926x; 1.4140x over previous
//
#include <hip/hip_runtime.h>
#include <math.h>

#define N_NODES 100000
#define N_EDGES 1600000
#define IN_F 64
#define OUT_F 64

// KAN GEMM K layout: k = (path*64 + i)*10 + c; c=0..7 spline bases, c=8 silu,
// c=9 zero pad. K'=1280. Chunk = 16 in-feats = 160 k = 5 MFMA K-steps of 32.
// 8 chunks (4 per path). Features single bf16 (RNE).
#define K_SLOT 10
#define CH_IF 16
#define CH_K 160
#define AST 168            // LDS row stride in bf16 elems (336 B, 16B-aligned)
#define NB 128             // nodes per block
#define NTHR 512

#define DEG_PAD 100352                   // 98*1024 floats
#define WG_U16 (8 * OUT_F * AST)         // 86016 bf16 = padded per-chunk W images
#define WG_SLOTS (WG_U16 / 2)            // 43008 f32 slots
#define ROWPTR_SLOTS 100352
#define SUMS_SLOTS 128
#define CSR_SLOTS N_EDGES
#define AGG_ELEMS (N_NODES * IN_F)

typedef __attribute__((ext_vector_type(8))) short bf16x8;
typedef __attribute__((ext_vector_type(4))) float f32x4;

__device__ __forceinline__ unsigned int bf16_rne(float v) {
    unsigned int u = __float_as_uint(v);
    u += 0x7FFFu + ((u >> 16) & 1u);
    return u >> 16;
}

__global__ void deg_kernel(const int* __restrict__ ei, float* __restrict__ deg) {
    int e = blockIdx.x * blockDim.x + threadIdx.x;
    if (e < N_EDGES) atomicAdd(&deg[ei[N_EDGES + e]], 1.0f);
}

__global__ void dinv_kernel(float* __restrict__ deg) {
    int n = blockIdx.x * blockDim.x + threadIdx.x;
    if (n < N_NODES) {
        float d = deg[n];
        deg[n] = (d > 0.0f) ? rsqrtf(d) : 0.0f;
    }
}

// ---- 3-kernel exclusive scan of deg -> rowptr ----
__global__ void scan_part(const float* __restrict__ deg, int* __restrict__ rowptr,
                          int* __restrict__ bsums) {
    __shared__ int tmp[1024];
    int t = threadIdx.x;
    int gi = blockIdx.x * 1024 + t;
    int v = (int)deg[gi];
    tmp[t] = v;
    __syncthreads();
    for (int off = 1; off < 1024; off <<= 1) {
        int add = (t >= off) ? tmp[t - off] : 0;
        __syncthreads();
        tmp[t] += add;
        __syncthreads();
    }
    rowptr[gi] = tmp[t] - v;
    if (t == 1023) bsums[blockIdx.x] = tmp[t];
}

__global__ void scan_sums(int* __restrict__ bsums) {
    __shared__ int tmp[128];
    int t = threadIdx.x;
    int v = (t < DEG_PAD / 1024) ? bsums[t] : 0;
    tmp[t] = v;
    __syncthreads();
    for (int off = 1; off < 128; off <<= 1) {
        int add = (t >= off) ? tmp[t - off] : 0;
        __syncthreads();
        tmp[t] += add;
        __syncthreads();
    }
    if (t < DEG_PAD / 1024) bsums[t] = tmp[t] - v;
}

__global__ void scan_add(int* __restrict__ rowptr, const int* __restrict__ bsums) {
    int gi = blockIdx.x * 1024 + threadIdx.x;
    rowptr[gi] += bsums[blockIdx.x];
}

__global__ void fill_kernel(const int* __restrict__ ei, int* __restrict__ rowptr,
                            int* __restrict__ csr) {
    int e = blockIdx.x * blockDim.x + threadIdx.x;
    if (e >= N_EDGES) return;
    int s = ei[e];
    int d = ei[N_EDGES + e];
    int pos = atomicAdd(&rowptr[d], 1);
    csr[pos] = s;
}

// gather: one wave per dst node, lane = feature
__global__ __launch_bounds__(256)
void gather_kernel(const float* __restrict__ x, const int* __restrict__ csr,
                   const int* __restrict__ rowptr, const float* __restrict__ dinv,
                   float* __restrict__ agg) {
    int wid = (int)((blockIdx.x * 256 + threadIdx.x) >> 6);
    int lane = threadIdx.x & 63;
    if (wid >= N_NODES) return;
    int end = rowptr[wid];
    int start = (wid == 0) ? 0 : rowptr[wid - 1];
    float acc = 0.0f;
    int j = start;
    for (; j + 3 < end; j += 4) {
        int s0 = csr[j], s1 = csr[j + 1], s2 = csr[j + 2], s3 = csr[j + 3];
        float a0 = x[s0 * 64 + lane] * dinv[s0];
        float a1 = x[s1 * 64 + lane] * dinv[s1];
        float a2 = x[s2 * 64 + lane] * dinv[s2];
        float a3 = x[s3 * 64 + lane] * dinv[s3];
        acc += a0 + a1 + a2 + a3;
    }
    for (; j < end; ++j) {
        int s = csr[j];
        acc += x[s * 64 + lane] * dinv[s];
    }
    agg[wid * 64 + lane] = acc * dinv[wid];
}

// fallback: one wave per edge, f32 atomics (only if ws too small for CSR)
__global__ void scatter_kernel(const float* __restrict__ x, const int* __restrict__ ei,
                               const float* __restrict__ dinv, float* __restrict__ agg) {
    long long gtid = (long long)blockIdx.x * blockDim.x + threadIdx.x;
    int wid = (int)(gtid >> 6);
    int lane = threadIdx.x & 63;
    if (wid >= N_EDGES) return;
    int s = ei[wid];
    int d = ei[N_EDGES + wid];
    float c = dinv[s] * dinv[d];
    atomicAdd(&agg[d * 64 + lane], x[s * 64 + lane] * c);
}

// Wt_g[ch][o][0..167] bf16: kk<160 -> i = i0(ch)+kk/10, c = kk%10;
// c==8 -> base_w, c==9 -> 0, else spline_w[o][i][c]. kk>=160 -> 0.
__global__ void wprep_kernel(const float* __restrict__ bwl, const float* __restrict__ swl,
                             const float* __restrict__ bwc, const float* __restrict__ swc,
                             unsigned short* __restrict__ Wt) {
    int gid = blockIdx.x * blockDim.x + threadIdx.x;
    if (gid >= 8 * OUT_F * AST) return;
    int ch = gid / (OUT_F * AST);
    int rem = gid - ch * (OUT_F * AST);
    int o = rem / AST;
    int kk = rem - o * AST;
    float v = 0.0f;
    if (kk < CH_K) {
        int iL = kk / K_SLOT;
        int c = kk - iL * K_SLOT;
        int i = (ch & 3) * CH_IF + iL;
        int path = ch >> 2;
        const float* bw = path ? bwc : bwl;
        const float* sw = path ? swc : swl;
        if (c == 8) v = bw[o * IN_F + i];
        else if (c < 8) v = sw[o * 512 + i * 8 + c];
    }
    Wt[gid] = (unsigned short)bf16_rne(v);
}

// MFMA KAN: 128 nodes/block, 8 waves, wave -> 16 nodes x 64 outs.
// Safe if agg aliases out: agg reads (chunks 4..7) precede epilogue out writes;
// blocks own disjoint 128-node row ranges.
__global__ __launch_bounds__(NTHR, 4)
void kan_mfma_kernel(const float* __restrict__ x, const float* __restrict__ agg,
                     const unsigned short* __restrict__ Wt, float* __restrict__ out) {
    __shared__ __align__(16) unsigned short A_lds[NB * AST];     // 43008 B
    __shared__ __align__(16) unsigned short W_lds[OUT_F * AST];  // 21504 B

    int tid = threadIdx.x;
    int nbase = blockIdx.x * NB;
    int wid = tid >> 6;
    int lane = tid & 63;

    f32x4 acc[4];
#pragma unroll
    for (int t = 0; t < 4; ++t) acc[t] = (f32x4){0.f, 0.f, 0.f, 0.f};

    for (int chunk = 0; chunk < 8; ++chunk) {
        int path = chunk >> 2;
        int i0 = (chunk & 3) * CH_IF;
        const float* src = path ? agg : x;

        // ---- stage weights: pure coalesced u32 copy of padded image
        {
            const unsigned int* wg = (const unsigned int*)&Wt[chunk * OUT_F * AST];
            unsigned int* wl = (unsigned int*)&W_lds[0];
            for (int f = tid; f < OUT_F * AST / 2; f += NTHR) wl[f] = wg[f];
        }

        // ---- features: node = tid&127, grp = tid>>7 covers 4 in-feats
        {
            int n = tid & (NB - 1);
            int grp = tid >> 7;
            int node = nbase + n;
            float4 v4 = make_float4(0.f, 0.f, 0.f, 0.f);
            if (node < N_NODES) v4 = *(const float4*)&src[node * 64 + i0 + grp * 4];
            float vv[4] = {v4.x, v4.y, v4.z, v4.w};
            unsigned short* Arow = &A_lds[n * AST];
#pragma unroll
            for (int jj = 0; jj < 4; ++jj) {
                int iL = grp * 4 + jj;
                float v = vv[jj];
                unsigned int* Au = (unsigned int*)(Arow + iL * K_SLOT);  // 20B-aligned? 20*iL mult of 4 ✓
                // zero bases (slots 0..7), write silu (slot 8) + pad 0 (slot 9)
                float sig = __builtin_amdgcn_rcpf(1.0f + __expf(-v));
                Au[0] = 0u; Au[1] = 0u; Au[2] = 0u; Au[3] = 0u;
                Au[4] = bf16_rne(v * sig);
                // closed-form cubic B-spline: cell m, local t in [0,1)
                float s5 = (v + 2.2f) * 2.5f;
                float fm = floorf(s5);
                int m = (int)fm;
                if (m >= 0 && m <= 10) {
                    float t = s5 - fm;
                    float omt = 1.0f - t;
                    float t2 = t * t, t3 = t2 * t;
                    float n0 = omt * omt * omt * (1.0f / 6.0f);
                    float n3 = t3 * (1.0f / 6.0f);
                    float n1 = 0.66666666f - t2 + 0.5f * t3;
                    float n2 = 1.0f - n0 - n1 - n3;
                    unsigned short* As = Arow + iL * K_SLOT;
                    if (m >= 3)           As[m - 3] = (unsigned short)bf16_rne(n0);
                    if (m >= 2 && m <= 9) As[m - 2] = (unsigned short)bf16_rne(n1);
                    if (m >= 1 && m <= 8) As[m - 1] = (unsigned short)bf16_rne(n2);
                    if (m <= 7)           As[m]     = (unsigned short)bf16_rne(n3);
                }
            }
        }
        __syncthreads();

        // ---- MFMA: 5 K-steps of 32
        {
            int arow = (wid << 4) + (lane & 15);
            int kfrag = (lane >> 4) * 8;
            const unsigned short* Abase = &A_lds[arow * AST + kfrag];
            int bcol = lane & 15;
#pragma unroll
            for (int s = 0; s < 5; ++s) {
                bf16x8 a = *(const bf16x8*)(Abase + s * 32);
#pragma unroll
                for (int t = 0; t < 4; ++t) {
                    bf16x8 b = *(const bf16x8*)(&W_lds[(t * 16 + bcol) * AST + kfrag + s * 32]);
                    acc[t] = __builtin_amdgcn_mfma_f32_16x16x32_bf16(a, b, acc[t], 0, 0, 0);
                }
            }
        }
        __syncthreads();
    }

    // ---- epilogue: C/D layout col=lane&15, row=(lane>>4)*4+reg
#pragma unroll
    for (int t = 0; t < 4; ++t) {
#pragma unroll
        for (int r = 0; r < 4; ++r) {
            int node = nbase + (wid << 4) + (lane >> 4) * 4 + r;
            if (node < N_NODES) out[node * 64 + t * 16 + (lane & 15)] = acc[t][r];
        }
    }
}

extern "C" void kernel_launch(void* const* d_in, const int* in_sizes, int n_in,
                              void* d_out, int out_size, void* d_ws, size_t ws_size,
                              hipStream_t stream) {
    const float* x   = (const float*)d_in[0];
    const float* bwl = (const float*)d_in[1];
    const float* swl = (const float*)d_in[2];
    const float* bwc = (const float*)d_in[3];
    const float* swc = (const float*)d_in[4];
    const int*   ei  = (const int*)d_in[5];
    float* out = (float*)d_out;

    float* ws  = (float*)d_ws;
    float* deg = ws;
    unsigned short* Wt = (unsigned short*)(ws + DEG_PAD);
    int* rowptr = (int*)(ws + DEG_PAD + WG_SLOTS);
    int* bsums  = rowptr + ROWPTR_SLOTS;
    int* csr    = bsums + SUMS_SLOTS;

    const size_t csr_end = (size_t)DEG_PAD + WG_SLOTS + ROWPTR_SLOTS + SUMS_SLOTS + CSR_SLOTS;
    const bool has_csr   = ws_size >= csr_end * sizeof(float);
    const size_t small_end = (size_t)DEG_PAD + WG_SLOTS;
    const size_t agg_base  = has_csr ? csr_end : small_end;
    const bool agg_in_ws   = ws_size >= (agg_base + (size_t)AGG_ELEMS) * sizeof(float);
    float* agg = agg_in_ws ? (ws + agg_base) : out;

    hipMemsetAsync(deg, 0, (size_t)DEG_PAD * sizeof(float), stream);

    deg_kernel<<<(N_EDGES + 255) / 256, 256, 0, stream>>>(ei, deg);

    if (has_csr) {
        scan_part<<<DEG_PAD / 1024, 1024, 0, stream>>>(deg, rowptr, bsums);
        scan_sums<<<1, 128, 0, stream>>>(bsums);
        scan_add<<<DEG_PAD / 1024, 1024, 0, stream>>>(rowptr, bsums);
        dinv_kernel<<<(N_NODES + 255) / 256, 256, 0, stream>>>(deg);
        fill_kernel<<<(N_EDGES + 255) / 256, 256, 0, stream>>>(ei, rowptr, csr);
        gather_kernel<<<(N_NODES * 64 + 255) / 256, 256, 0, stream>>>(x, csr, rowptr, deg, agg);
    } else {
        dinv_kernel<<<(N_NODES + 255) / 256, 256, 0, stream>>>(deg);
        hipMemsetAsync(agg, 0, (size_t)AGG_ELEMS * sizeof(float), stream);
        long long scatter_threads = (long long)N_EDGES * 64;
        int scatter_blocks = (int)((scatter_threads + 255) / 256);
        scatter_kernel<<<scatter_blocks, 256, 0, stream>>>(x, ei, deg, agg);
    }

    wprep_kernel<<<(8 * OUT_F * AST + 255) / 256, 256, 0, stream>>>(bwl, swl, bwc, swc, Wt);

    kan_mfma_kernel<<<(N_NODES + NB - 1) / NB, NTHR, 0, stream>>>(x, agg, Wt, out);
}

// Round 11
// 234.375 us; speedup vs baseline: 4.2414x; 1.6359x over previous
//
#include <hip/hip_runtime.h>
#include <math.h>

#define N_NODES 100000
#define N_EDGES 1600000
#define IN_F 64
#define OUT_F 64

// KAN GEMM K layout: k = (path*64 + i)*10 + c; c=0..7 spline bases, c=8 silu,
// c=9 zero pad. K'=1280. Chunk = 16 in-feats = 160 k = 5 MFMA K-steps of 32.
#define K_SLOT 10
#define CH_IF 16
#define CH_K 160
#define AST 168            // LDS row stride in bf16 elems
#define NB 128             // nodes per block (kan)
#define NTHR 512

// bucketed CSR build
#define NBUCK 256
#define BSH 9              // bucket = dst>>9, 512 nodes per bucket
#define BUCK_N 512
#define EPT 8
#define EPB 2048           // edges per bin-block

// ws layout (f32 slots)
#define NODES_PAD 100352
#define WG_SLOTS 43008                   // 86016 bf16 padded W images
#define OFF_DINV 0
#define OFF_ROWPTR (OFF_DINV + NODES_PAD)
#define OFF_ROWEND (OFF_ROWPTR + NODES_PAD)
#define OFF_WT (OFF_ROWEND + NODES_PAD)
#define OFF_BUCK (OFF_WT + WG_SLOTS)     // bc[256] bb[256] bf[256] pad->1024
#define OFF_CSR (OFF_BUCK + 1024)
#define FIXED_SLOTS (OFF_CSR + N_EDGES)  // 1,945,088
#define AGG_ELEMS (N_NODES * IN_F)

typedef __attribute__((ext_vector_type(8))) short bf16x8;
typedef __attribute__((ext_vector_type(4))) float f32x4;

__device__ __forceinline__ unsigned int bf16_rne(float v) {
    unsigned int u = __float_as_uint(v);
    u += 0x7FFFu + ((u >> 16) & 1u);
    return u >> 16;
}

// ---- bucketed CSR build ----
__global__ __launch_bounds__(256)
void bucket_count_kernel(const int* __restrict__ dstp, int* __restrict__ bc) {
    __shared__ int lh[NBUCK];
    int t = threadIdx.x;
    lh[t] = 0;
    __syncthreads();
    for (int e = blockIdx.x * 256 + t; e < N_EDGES; e += gridDim.x * 256)
        atomicAdd(&lh[dstp[e] >> BSH], 1);
    __syncthreads();
    if (lh[t]) atomicAdd(&bc[t], lh[t]);
}

__global__ void bucket_scan_kernel(const int* __restrict__ bc, int* __restrict__ bb,
                                   int* __restrict__ bf) {
    __shared__ int sb[NBUCK];
    int t = threadIdx.x;
    int v = bc[t];
    sb[t] = v;
    __syncthreads();
    for (int off = 1; off < NBUCK; off <<= 1) {
        int add = (t >= off) ? sb[t - off] : 0;
        __syncthreads();
        sb[t] += add;
        __syncthreads();
    }
    int excl = sb[t] - v;
    bb[t] = excl;
    bf[t] = excl;
}

__global__ __launch_bounds__(256)
void bucket_bin_kernel(const int* __restrict__ ei, int* __restrict__ bf,
                       int2* __restrict__ pairs) {
    __shared__ int lh[NBUCK];
    __shared__ int lbase[NBUCK];
    int t = threadIdx.x;
    lh[t] = 0;
    __syncthreads();
    int e0 = blockIdx.x * EPB;
    int d[EPT], s[EPT], lp[EPT];
#pragma unroll
    for (int k = 0; k < EPT; ++k) {
        int e = e0 + k * 256 + t;
        bool ok = e < N_EDGES;
        d[k] = ok ? ei[N_EDGES + e] : -1;
        s[k] = ok ? ei[e] : 0;
        lp[k] = ok ? atomicAdd(&lh[d[k] >> BSH], 1) : 0;
    }
    __syncthreads();
    if (lh[t]) lbase[t] = atomicAdd(&bf[t], lh[t]);
    __syncthreads();
#pragma unroll
    for (int k = 0; k < EPT; ++k) {
        if (d[k] >= 0) {
            int b = d[k] >> BSH;
            pairs[lbase[b] + lp[k]] = make_int2(d[k], s[k]);
        }
    }
}

// one block per bucket: local deg hist, scan -> rowptr/rowend/dinv, csr fill (L2-local)
__global__ __launch_bounds__(BUCK_N)
void bucket_build_kernel(const int2* __restrict__ pairs, const int* __restrict__ bc,
                         const int* __restrict__ bb, int* __restrict__ rowptr,
                         int* __restrict__ rowend, float* __restrict__ dinv,
                         int* __restrict__ csr) {
    __shared__ int ldeg[BUCK_N];
    __shared__ int sb[BUCK_N];
    __shared__ int lpos[BUCK_N];
    int t = threadIdx.x;
    int b = blockIdx.x;
    int cnt = bc[b];
    int base = bb[b];
    ldeg[t] = 0;
    __syncthreads();
    for (int j = t; j < cnt; j += BUCK_N) atomicAdd(&ldeg[pairs[base + j].x & (BUCK_N - 1)], 1);
    __syncthreads();
    int v = ldeg[t];
    sb[t] = v;
    __syncthreads();
    for (int off = 1; off < BUCK_N; off <<= 1) {
        int add = (t >= off) ? sb[t - off] : 0;
        __syncthreads();
        sb[t] += add;
        __syncthreads();
    }
    int excl = sb[t] - v;
    int node = (b << BSH) + t;
    if (node < N_NODES) {
        rowptr[node] = base + excl;
        rowend[node] = base + excl + v;
        dinv[node] = (v > 0) ? rsqrtf((float)v) : 0.0f;
    }
    lpos[t] = base + excl;
    __syncthreads();
    for (int j = t; j < cnt; j += BUCK_N) {
        int2 p = pairs[base + j];
        int pos = atomicAdd(&lpos[p.x & (BUCK_N - 1)], 1);
        csr[pos] = p.y;
    }
}

// gather: one wave per dst node, lane = feature
__global__ __launch_bounds__(256)
void gather_kernel(const float* __restrict__ x, const int* __restrict__ csr,
                   const int* __restrict__ rowptr, const int* __restrict__ rowend,
                   const float* __restrict__ dinv, float* __restrict__ agg) {
    int wid = (int)((blockIdx.x * 256 + threadIdx.x) >> 6);
    int lane = threadIdx.x & 63;
    if (wid >= N_NODES) return;
    int start = rowptr[wid];
    int end = rowend[wid];
    float acc = 0.0f;
    int j = start;
    for (; j + 3 < end; j += 4) {
        int s0 = csr[j], s1 = csr[j + 1], s2 = csr[j + 2], s3 = csr[j + 3];
        float a0 = x[s0 * 64 + lane] * dinv[s0];
        float a1 = x[s1 * 64 + lane] * dinv[s1];
        float a2 = x[s2 * 64 + lane] * dinv[s2];
        float a3 = x[s3 * 64 + lane] * dinv[s3];
        acc += a0 + a1 + a2 + a3;
    }
    for (; j < end; ++j) {
        int s = csr[j];
        acc += x[s * 64 + lane] * dinv[s];
    }
    agg[wid * 64 + lane] = acc * dinv[wid];
}

// ---- fallback (ws too small): f32 atomic scatter ----
__global__ void deg_kernel(const int* __restrict__ ei, float* __restrict__ deg) {
    int e = blockIdx.x * blockDim.x + threadIdx.x;
    if (e < N_EDGES) atomicAdd(&deg[ei[N_EDGES + e]], 1.0f);
}
__global__ void dinv_kernel(float* __restrict__ deg) {
    int n = blockIdx.x * blockDim.x + threadIdx.x;
    if (n < N_NODES) {
        float d = deg[n];
        deg[n] = (d > 0.0f) ? rsqrtf(d) : 0.0f;
    }
}
__global__ void scatter_kernel(const float* __restrict__ x, const int* __restrict__ ei,
                               const float* __restrict__ dinv, float* __restrict__ agg) {
    long long gtid = (long long)blockIdx.x * blockDim.x + threadIdx.x;
    int wid = (int)(gtid >> 6);
    int lane = threadIdx.x & 63;
    if (wid >= N_EDGES) return;
    int s = ei[wid];
    int d = ei[N_EDGES + wid];
    float c = dinv[s] * dinv[d];
    atomicAdd(&agg[d * 64 + lane], x[s * 64 + lane] * c);
}

// Wt_g[ch][o][0..167] bf16
__global__ void wprep_kernel(const float* __restrict__ bwl, const float* __restrict__ swl,
                             const float* __restrict__ bwc, const float* __restrict__ swc,
                             unsigned short* __restrict__ Wt) {
    int gid = blockIdx.x * blockDim.x + threadIdx.x;
    if (gid >= 8 * OUT_F * AST) return;
    int ch = gid / (OUT_F * AST);
    int rem = gid - ch * (OUT_F * AST);
    int o = rem / AST;
    int kk = rem - o * AST;
    float v = 0.0f;
    if (kk < CH_K) {
        int iL = kk / K_SLOT;
        int c = kk - iL * K_SLOT;
        int i = (ch & 3) * CH_IF + iL;
        int path = ch >> 2;
        const float* bw = path ? bwc : bwl;
        const float* sw = path ? swc : swl;
        if (c == 8) v = bw[o * IN_F + i];
        else if (c < 8) v = sw[o * 512 + i * 8 + c];
    }
    Wt[gid] = (unsigned short)bf16_rne(v);
}

// MFMA KAN: 128 nodes/block, 8 waves, wave -> 16 nodes x 64 outs.
// Safe if agg aliases out: agg reads (chunks 4..7) precede epilogue out writes;
// blocks own disjoint 128-node row ranges.
__global__ __launch_bounds__(NTHR, 4)
void kan_mfma_kernel(const float* __restrict__ x, const float* __restrict__ agg,
                     const unsigned short* __restrict__ Wt, float* __restrict__ out) {
    __shared__ __align__(16) unsigned short A_lds[NB * AST];     // 43008 B
    __shared__ __align__(16) unsigned short W_lds[OUT_F * AST];  // 21504 B

    int tid = threadIdx.x;
    int nbase = blockIdx.x * NB;
    int wid = tid >> 6;
    int lane = tid & 63;

    f32x4 acc[4];
#pragma unroll
    for (int t = 0; t < 4; ++t) acc[t] = (f32x4){0.f, 0.f, 0.f, 0.f};

    for (int chunk = 0; chunk < 8; ++chunk) {
        int path = chunk >> 2;
        int i0 = (chunk & 3) * CH_IF;
        const float* src = path ? agg : x;

        {
            const unsigned int* wg = (const unsigned int*)&Wt[chunk * OUT_F * AST];
            unsigned int* wl = (unsigned int*)&W_lds[0];
            for (int f = tid; f < OUT_F * AST / 2; f += NTHR) wl[f] = wg[f];
        }

        {
            int n = tid & (NB - 1);
            int grp = tid >> 7;
            int node = nbase + n;
            float4 v4 = make_float4(0.f, 0.f, 0.f, 0.f);
            if (node < N_NODES) v4 = *(const float4*)&src[node * 64 + i0 + grp * 4];
            float vv[4] = {v4.x, v4.y, v4.z, v4.w};
            unsigned short* Arow = &A_lds[n * AST];
#pragma unroll
            for (int jj = 0; jj < 4; ++jj) {
                int iL = grp * 4 + jj;
                float v = vv[jj];
                unsigned int* Au = (unsigned int*)(Arow + iL * K_SLOT);
                float sig = __builtin_amdgcn_rcpf(1.0f + __expf(-v));
                Au[0] = 0u; Au[1] = 0u; Au[2] = 0u; Au[3] = 0u;
                Au[4] = bf16_rne(v * sig);
                float s5 = (v + 2.2f) * 2.5f;
                float fm = floorf(s5);
                int m = (int)fm;
                if (m >= 0 && m <= 10) {
                    float t = s5 - fm;
                    float omt = 1.0f - t;
                    float t2 = t * t, t3 = t2 * t;
                    float n0 = omt * omt * omt * (1.0f / 6.0f);
                    float n3 = t3 * (1.0f / 6.0f);
                    float n1 = 0.66666666f - t2 + 0.5f * t3;
                    float n2 = 1.0f - n0 - n1 - n3;
                    unsigned short* As = Arow + iL * K_SLOT;
                    if (m >= 3)           As[m - 3] = (unsigned short)bf16_rne(n0);
                    if (m >= 2 && m <= 9) As[m - 2] = (unsigned short)bf16_rne(n1);
                    if (m >= 1 && m <= 8) As[m - 1] = (unsigned short)bf16_rne(n2);
                    if (m <= 7)           As[m]     = (unsigned short)bf16_rne(n3);
                }
            }
        }
        __syncthreads();

        {
            int arow = (wid << 4) + (lane & 15);
            int kfrag = (lane >> 4) * 8;
            const unsigned short* Abase = &A_lds[arow * AST + kfrag];
            int bcol = lane & 15;
#pragma unroll
            for (int s = 0; s < 5; ++s) {
                bf16x8 a = *(const bf16x8*)(Abase + s * 32);
#pragma unroll
                for (int t = 0; t < 4; ++t) {
                    bf16x8 b = *(const bf16x8*)(&W_lds[(t * 16 + bcol) * AST + kfrag + s * 32]);
                    acc[t] = __builtin_amdgcn_mfma_f32_16x16x32_bf16(a, b, acc[t], 0, 0, 0);
                }
            }
        }
        __syncthreads();
    }

#pragma unroll
    for (int t = 0; t < 4; ++t) {
#pragma unroll
        for (int r = 0; r < 4; ++r) {
            int node = nbase + (wid << 4) + (lane >> 4) * 4 + r;
            if (node < N_NODES) out[node * 64 + t * 16 + (lane & 15)] = acc[t][r];
        }
    }
}

extern "C" void kernel_launch(void* const* d_in, const int* in_sizes, int n_in,
                              void* d_out, int out_size, void* d_ws, size_t ws_size,
                              hipStream_t stream) {
    const float* x   = (const float*)d_in[0];
    const float* bwl = (const float*)d_in[1];
    const float* swl = (const float*)d_in[2];
    const float* bwc = (const float*)d_in[3];
    const float* swc = (const float*)d_in[4];
    const int*   ei  = (const int*)d_in[5];
    float* out = (float*)d_out;

    float* ws = (float*)d_ws;
    float* dinv = ws + OFF_DINV;
    int* rowptr = (int*)(ws + OFF_ROWPTR);
    int* rowend = (int*)(ws + OFF_ROWEND);
    unsigned short* Wt = (unsigned short*)(ws + OFF_WT);
    int* bc = (int*)(ws + OFF_BUCK);
    int* bb = bc + NBUCK;
    int* bf = bb + NBUCK;
    int* csr = (int*)(ws + OFF_CSR);

    const bool has_csr = ws_size >= (size_t)FIXED_SLOTS * sizeof(float);
    const bool agg_in_ws = ws_size >= ((size_t)FIXED_SLOTS + AGG_ELEMS) * sizeof(float);
    float* agg = (has_csr && agg_in_ws) ? (ws + FIXED_SLOTS) : out;
    int2* pairs = (int2*)agg;   // overlay: pairs dead before gather writes agg

    if (has_csr) {
        hipMemsetAsync(bc, 0, NBUCK * sizeof(int), stream);
        bucket_count_kernel<<<1024, 256, 0, stream>>>(ei + N_EDGES, bc);
        bucket_scan_kernel<<<1, NBUCK, 0, stream>>>(bc, bb, bf);
        bucket_bin_kernel<<<(N_EDGES + EPB - 1) / EPB, 256, 0, stream>>>(ei, bf, pairs);
        bucket_build_kernel<<<NBUCK, BUCK_N, 0, stream>>>(pairs, bc, bb, rowptr, rowend, dinv, csr);
        gather_kernel<<<(N_NODES * 64 + 255) / 256, 256, 0, stream>>>(x, csr, rowptr, rowend, dinv, agg);
    } else {
        float* deg = dinv;
        hipMemsetAsync(deg, 0, (size_t)NODES_PAD * sizeof(float), stream);
        deg_kernel<<<(N_EDGES + 255) / 256, 256, 0, stream>>>(ei, deg);
        dinv_kernel<<<(N_NODES + 255) / 256, 256, 0, stream>>>(deg);
        hipMemsetAsync(agg, 0, (size_t)AGG_ELEMS * sizeof(float), stream);
        long long scatter_threads = (long long)N_EDGES * 64;
        int scatter_blocks = (int)((scatter_threads + 255) / 256);
        scatter_kernel<<<scatter_blocks, 256, 0, stream>>>(x, ei, deg, agg);
    }

    wprep_kernel<<<(8 * OUT_F * AST + 255) / 256, 256, 0, stream>>>(bwl, swl, bwc, swc, Wt);

    kan_mfma_kernel<<<(N_NODES + NB - 1) / NB, NTHR, 0, stream>>>(x, agg, Wt, out);
}

// Round 12
// 233.632 us; speedup vs baseline: 4.2549x; 1.0032x over previous
//
#include <hip/hip_runtime.h>
#include <math.h>

#define N_NODES 100000
#define N_EDGES 1600000
#define IN_F 64
#define OUT_F 64

// KAN GEMM K layout: k = (path*64 + i)*10 + c; c=0..7 spline bases, c=8 silu,
// c=9 zero pad. K'=1280. Chunk = 16 in-feats = 160 k = 5 MFMA K-steps of 32.
#define K_SLOT 10
#define CH_IF 16
#define CH_K 160
#define AST 172            // LDS row stride in bf16 elems; 86 u32 == 22 mod 32 ->
                           // bank period 16 (was 168 -> period 8 -> 8-way conflicts).
                           // Rows are 8B-aligned only: fragment loads = 2x ds_read_b64.
#define NB 128             // nodes per block (kan)
#define NTHR 512

// bucketed CSR build
#define NBUCK 256
#define BSH 9              // bucket = dst>>9, 512 nodes per bucket
#define BUCK_N 512
#define EPT 8
#define EPB 2048           // edges per bin-block

// ws layout (f32 slots)
#define NODES_PAD 100352
#define WG_SLOTS (8 * OUT_F * AST / 2)   // padded per-chunk W images (bf16/2)
#define OFF_DINV 0
#define OFF_ROWPTR (OFF_DINV + NODES_PAD)
#define OFF_ROWEND (OFF_ROWPTR + NODES_PAD)
#define OFF_WT (OFF_ROWEND + NODES_PAD)
#define OFF_BUCK (OFF_WT + WG_SLOTS)     // bc[256] bb[256] bf[256] pad->1024
#define OFF_CSR (OFF_BUCK + 1024)
#define FIXED_SLOTS (OFF_CSR + N_EDGES)
#define AGG_ELEMS (N_NODES * IN_F)

typedef __attribute__((ext_vector_type(8))) short bf16x8;
typedef __attribute__((ext_vector_type(4))) short bf16x4;
typedef __attribute__((ext_vector_type(4))) float f32x4;

__device__ __forceinline__ unsigned int bf16_rne(float v) {
    unsigned int u = __float_as_uint(v);
    u += 0x7FFFu + ((u >> 16) & 1u);
    return u >> 16;
}

// ---- bucketed CSR build ----
__global__ __launch_bounds__(256)
void bucket_count_kernel(const int* __restrict__ dstp, int* __restrict__ bc) {
    __shared__ int lh[NBUCK];
    int t = threadIdx.x;
    lh[t] = 0;
    __syncthreads();
    for (int e = blockIdx.x * 256 + t; e < N_EDGES; e += gridDim.x * 256)
        atomicAdd(&lh[dstp[e] >> BSH], 1);
    __syncthreads();
    if (lh[t]) atomicAdd(&bc[t], lh[t]);
}

__global__ void bucket_scan_kernel(const int* __restrict__ bc, int* __restrict__ bb,
                                   int* __restrict__ bf) {
    __shared__ int sb[NBUCK];
    int t = threadIdx.x;
    int v = bc[t];
    sb[t] = v;
    __syncthreads();
    for (int off = 1; off < NBUCK; off <<= 1) {
        int add = (t >= off) ? sb[t - off] : 0;
        __syncthreads();
        sb[t] += add;
        __syncthreads();
    }
    int excl = sb[t] - v;
    bb[t] = excl;
    bf[t] = excl;
}

__global__ __launch_bounds__(256)
void bucket_bin_kernel(const int* __restrict__ ei, int* __restrict__ bf,
                       int2* __restrict__ pairs) {
    __shared__ int lh[NBUCK];
    __shared__ int lbase[NBUCK];
    int t = threadIdx.x;
    lh[t] = 0;
    __syncthreads();
    int e0 = blockIdx.x * EPB;
    int d[EPT], s[EPT], lp[EPT];
#pragma unroll
    for (int k = 0; k < EPT; ++k) {
        int e = e0 + k * 256 + t;
        bool ok = e < N_EDGES;
        d[k] = ok ? ei[N_EDGES + e] : -1;
        s[k] = ok ? ei[e] : 0;
        lp[k] = ok ? atomicAdd(&lh[d[k] >> BSH], 1) : 0;
    }
    __syncthreads();
    if (lh[t]) lbase[t] = atomicAdd(&bf[t], lh[t]);
    __syncthreads();
#pragma unroll
    for (int k = 0; k < EPT; ++k) {
        if (d[k] >= 0) {
            int b = d[k] >> BSH;
            pairs[lbase[b] + lp[k]] = make_int2(d[k], s[k]);
        }
    }
}

// one block per bucket: local deg hist, scan -> rowptr/rowend/dinv, csr fill (L2-local)
__global__ __launch_bounds__(BUCK_N)
void bucket_build_kernel(const int2* __restrict__ pairs, const int* __restrict__ bc,
                         const int* __restrict__ bb, int* __restrict__ rowptr,
                         int* __restrict__ rowend, float* __restrict__ dinv,
                         int* __restrict__ csr) {
    __shared__ int ldeg[BUCK_N];
    __shared__ int sb[BUCK_N];
    __shared__ int lpos[BUCK_N];
    int t = threadIdx.x;
    int b = blockIdx.x;
    int cnt = bc[b];
    int base = bb[b];
    ldeg[t] = 0;
    __syncthreads();
    for (int j = t; j < cnt; j += BUCK_N) atomicAdd(&ldeg[pairs[base + j].x & (BUCK_N - 1)], 1);
    __syncthreads();
    int v = ldeg[t];
    sb[t] = v;
    __syncthreads();
    for (int off = 1; off < BUCK_N; off <<= 1) {
        int add = (t >= off) ? sb[t - off] : 0;
        __syncthreads();
        sb[t] += add;
        __syncthreads();
    }
    int excl = sb[t] - v;
    int node = (b << BSH) + t;
    if (node < N_NODES) {
        rowptr[node] = base + excl;
        rowend[node] = base + excl + v;
        dinv[node] = (v > 0) ? rsqrtf((float)v) : 0.0f;
    }
    lpos[t] = base + excl;
    __syncthreads();
    for (int j = t; j < cnt; j += BUCK_N) {
        int2 p = pairs[base + j];
        int pos = atomicAdd(&lpos[p.x & (BUCK_N - 1)], 1);
        csr[pos] = p.y;
    }
}

// gather: one wave per dst node, lane = feature
__global__ __launch_bounds__(256)
void gather_kernel(const float* __restrict__ x, const int* __restrict__ csr,
                   const int* __restrict__ rowptr, const int* __restrict__ rowend,
                   const float* __restrict__ dinv, float* __restrict__ agg) {
    int wid = (int)((blockIdx.x * 256 + threadIdx.x) >> 6);
    int lane = threadIdx.x & 63;
    if (wid >= N_NODES) return;
    int start = rowptr[wid];
    int end = rowend[wid];
    float acc = 0.0f;
    int j = start;
    for (; j + 3 < end; j += 4) {
        int s0 = csr[j], s1 = csr[j + 1], s2 = csr[j + 2], s3 = csr[j + 3];
        float a0 = x[s0 * 64 + lane] * dinv[s0];
        float a1 = x[s1 * 64 + lane] * dinv[s1];
        float a2 = x[s2 * 64 + lane] * dinv[s2];
        float a3 = x[s3 * 64 + lane] * dinv[s3];
        acc += a0 + a1 + a2 + a3;
    }
    for (; j < end; ++j) {
        int s = csr[j];
        acc += x[s * 64 + lane] * dinv[s];
    }
    agg[wid * 64 + lane] = acc * dinv[wid];
}

// ---- fallback (ws too small): f32 atomic scatter ----
__global__ void deg_kernel(const int* __restrict__ ei, float* __restrict__ deg) {
    int e = blockIdx.x * blockDim.x + threadIdx.x;
    if (e < N_EDGES) atomicAdd(&deg[ei[N_EDGES + e]], 1.0f);
}
__global__ void dinv_kernel(float* __restrict__ deg) {
    int n = blockIdx.x * blockDim.x + threadIdx.x;
    if (n < N_NODES) {
        float d = deg[n];
        deg[n] = (d > 0.0f) ? rsqrtf(d) : 0.0f;
    }
}
__global__ void scatter_kernel(const float* __restrict__ x, const int* __restrict__ ei,
                               const float* __restrict__ dinv, float* __restrict__ agg) {
    long long gtid = (long long)blockIdx.x * blockDim.x + threadIdx.x;
    int wid = (int)(gtid >> 6);
    int lane = threadIdx.x & 63;
    if (wid >= N_EDGES) return;
    int s = ei[wid];
    int d = ei[N_EDGES + wid];
    float c = dinv[s] * dinv[d];
    atomicAdd(&agg[d * 64 + lane], x[s * 64 + lane] * c);
}

// Wt_g[ch][o][0..AST-1] bf16: kk<160 -> i = i0(ch)+kk/10, c = kk%10;
// c==8 -> base_w, c==9 -> 0, else spline_w[o][i][c]. kk>=160 -> 0.
__global__ void wprep_kernel(const float* __restrict__ bwl, const float* __restrict__ swl,
                             const float* __restrict__ bwc, const float* __restrict__ swc,
                             unsigned short* __restrict__ Wt) {
    int gid = blockIdx.x * blockDim.x + threadIdx.x;
    if (gid >= 8 * OUT_F * AST) return;
    int ch = gid / (OUT_F * AST);
    int rem = gid - ch * (OUT_F * AST);
    int o = rem / AST;
    int kk = rem - o * AST;
    float v = 0.0f;
    if (kk < CH_K) {
        int iL = kk / K_SLOT;
        int c = kk - iL * K_SLOT;
        int i = (ch & 3) * CH_IF + iL;
        int path = ch >> 2;
        const float* bw = path ? bwc : bwl;
        const float* sw = path ? swc : swl;
        if (c == 8) v = bw[o * IN_F + i];
        else if (c < 8) v = sw[o * 512 + i * 8 + c];
    }
    Wt[gid] = (unsigned short)bf16_rne(v);
}

// MFMA KAN: 128 nodes/block, 8 waves, wave -> 16 nodes x 64 outs.
// Safe if agg aliases out: agg reads (chunks 4..7) precede epilogue out writes;
// blocks own disjoint 128-node row ranges.
__global__ __launch_bounds__(NTHR, 4)
void kan_mfma_kernel(const float* __restrict__ x, const float* __restrict__ agg,
                     const unsigned short* __restrict__ Wt, float* __restrict__ out) {
    __shared__ __align__(16) unsigned short A_lds[NB * AST];     // 44032 B
    __shared__ __align__(16) unsigned short W_lds[OUT_F * AST];  // 22016 B

    int tid = threadIdx.x;
    int nbase = blockIdx.x * NB;
    int wid = tid >> 6;
    int lane = tid & 63;

    f32x4 acc[4];
#pragma unroll
    for (int t = 0; t < 4; ++t) acc[t] = (f32x4){0.f, 0.f, 0.f, 0.f};

    for (int chunk = 0; chunk < 8; ++chunk) {
        int path = chunk >> 2;
        int i0 = (chunk & 3) * CH_IF;
        const float* src = path ? agg : x;

        {
            const unsigned int* wg = (const unsigned int*)&Wt[chunk * OUT_F * AST];
            unsigned int* wl = (unsigned int*)&W_lds[0];
            for (int f = tid; f < OUT_F * AST / 2; f += NTHR) wl[f] = wg[f];
        }

        {
            int n = tid & (NB - 1);
            int grp = tid >> 7;
            int node = nbase + n;
            float4 v4 = make_float4(0.f, 0.f, 0.f, 0.f);
            if (node < N_NODES) v4 = *(const float4*)&src[node * 64 + i0 + grp * 4];
            float vv[4] = {v4.x, v4.y, v4.z, v4.w};
            unsigned short* Arow = &A_lds[n * AST];
#pragma unroll
            for (int jj = 0; jj < 4; ++jj) {
                int iL = grp * 4 + jj;
                float v = vv[jj];
                unsigned int* Au = (unsigned int*)(Arow + iL * K_SLOT);
                float sig = __builtin_amdgcn_rcpf(1.0f + __expf(-v));
                Au[0] = 0u; Au[1] = 0u; Au[2] = 0u; Au[3] = 0u;
                Au[4] = bf16_rne(v * sig);
                float s5 = (v + 2.2f) * 2.5f;
                float fm = floorf(s5);
                int m = (int)fm;
                if (m >= 0 && m <= 10) {
                    float t = s5 - fm;
                    float omt = 1.0f - t;
                    float t2 = t * t, t3 = t2 * t;
                    float n0 = omt * omt * omt * (1.0f / 6.0f);
                    float n3 = t3 * (1.0f / 6.0f);
                    float n1 = 0.66666666f - t2 + 0.5f * t3;
                    float n2 = 1.0f - n0 - n1 - n3;
                    unsigned short* As = Arow + iL * K_SLOT;
                    if (m >= 3)           As[m - 3] = (unsigned short)bf16_rne(n0);
                    if (m >= 2 && m <= 9) As[m - 2] = (unsigned short)bf16_rne(n1);
                    if (m >= 1 && m <= 8) As[m - 1] = (unsigned short)bf16_rne(n2);
                    if (m <= 7)           As[m]     = (unsigned short)bf16_rne(n3);
                }
            }
        }
        __syncthreads();

        {
            int arow = (wid << 4) + (lane & 15);
            int kfrag = (lane >> 4) * 8;
            const unsigned short* Abase = &A_lds[arow * AST + kfrag];
            int bcol = lane & 15;
#pragma unroll
            for (int s = 0; s < 5; ++s) {
                // rows are 8B-aligned (AST=172): fragment = 2x ds_read_b64
                bf16x4 alo = *(const bf16x4*)(Abase + s * 32);
                bf16x4 ahi = *(const bf16x4*)(Abase + s * 32 + 4);
                bf16x8 a = __builtin_shufflevector(alo, ahi, 0, 1, 2, 3, 4, 5, 6, 7);
#pragma unroll
                for (int t = 0; t < 4; ++t) {
                    const unsigned short* Bp = &W_lds[(t * 16 + bcol) * AST + kfrag + s * 32];
                    bf16x4 blo = *(const bf16x4*)(Bp);
                    bf16x4 bhi = *(const bf16x4*)(Bp + 4);
                    bf16x8 b = __builtin_shufflevector(blo, bhi, 0, 1, 2, 3, 4, 5, 6, 7);
                    acc[t] = __builtin_amdgcn_mfma_f32_16x16x32_bf16(a, b, acc[t], 0, 0, 0);
                }
            }
        }
        __syncthreads();
    }

#pragma unroll
    for (int t = 0; t < 4; ++t) {
#pragma unroll
        for (int r = 0; r < 4; ++r) {
            int node = nbase + (wid << 4) + (lane >> 4) * 4 + r;
            if (node < N_NODES) out[node * 64 + t * 16 + (lane & 15)] = acc[t][r];
        }
    }
}

extern "C" void kernel_launch(void* const* d_in, const int* in_sizes, int n_in,
                              void* d_out, int out_size, void* d_ws, size_t ws_size,
                              hipStream_t stream) {
    const float* x   = (const float*)d_in[0];
    const float* bwl = (const float*)d_in[1];
    const float* swl = (const float*)d_in[2];
    const float* bwc = (const float*)d_in[3];
    const float* swc = (const float*)d_in[4];
    const int*   ei  = (const int*)d_in[5];
    float* out = (float*)d_out;

    float* ws = (float*)d_ws;
    float* dinv = ws + OFF_DINV;
    int* rowptr = (int*)(ws + OFF_ROWPTR);
    int* rowend = (int*)(ws + OFF_ROWEND);
    unsigned short* Wt = (unsigned short*)(ws + OFF_WT);
    int* bc = (int*)(ws + OFF_BUCK);
    int* bb = bc + NBUCK;
    int* bf = bb + NBUCK;
    int* csr = (int*)(ws + OFF_CSR);

    const bool has_csr = ws_size >= (size_t)FIXED_SLOTS * sizeof(float);
    const bool agg_in_ws = ws_size >= ((size_t)FIXED_SLOTS + AGG_ELEMS) * sizeof(float);
    float* agg = (has_csr && agg_in_ws) ? (ws + FIXED_SLOTS) : out;
    int2* pairs = (int2*)agg;   // overlay: pairs dead before gather writes agg

    if (has_csr) {
        hipMemsetAsync(bc, 0, NBUCK * sizeof(int), stream);
        bucket_count_kernel<<<1024, 256, 0, stream>>>(ei + N_EDGES, bc);
        bucket_scan_kernel<<<1, NBUCK, 0, stream>>>(bc, bb, bf);
        bucket_bin_kernel<<<(N_EDGES + EPB - 1) / EPB, 256, 0, stream>>>(ei, bf, pairs);
        bucket_build_kernel<<<NBUCK, BUCK_N, 0, stream>>>(pairs, bc, bb, rowptr, rowend, dinv, csr);
        gather_kernel<<<(N_NODES * 64 + 255) / 256, 256, 0, stream>>>(x, csr, rowptr, rowend, dinv, agg);
    } else {
        float* deg = dinv;
        hipMemsetAsync(deg, 0, (size_t)NODES_PAD * sizeof(float), stream);
        deg_kernel<<<(N_EDGES + 255) / 256, 256, 0, stream>>>(ei, deg);
        dinv_kernel<<<(N_NODES + 255) / 256, 256, 0, stream>>>(deg);
        hipMemsetAsync(agg, 0, (size_t)AGG_ELEMS * sizeof(float), stream);
        long long scatter_threads = (long long)N_EDGES * 64;
        int scatter_blocks = (int)((scatter_threads + 255) / 256);
        scatter_kernel<<<scatter_blocks, 256, 0, stream>>>(x, ei, deg, agg);
    }

    wprep_kernel<<<(8 * OUT_F * AST + 255) / 256, 256, 0, stream>>>(bwl, swl, bwc, swc, Wt);

    kan_mfma_kernel<<<(N_NODES + NB - 1) / NB, NTHR, 0, stream>>>(x, agg, Wt, out);
}

// Round 13
// 228.634 us; speedup vs baseline: 4.3479x; 1.0219x over previous
//
#include <hip/hip_runtime.h>
#include <math.h>

#define N_NODES 100000
#define N_EDGES 1600000
#define IN_F 64
#define OUT_F 64

// KAN GEMM K layout: k = (path*64 + i)*10 + c; c=0..7 spline bases, c=8 silu,
// c=9 zero pad. K'=1280. Chunk = 16 in-feats = 160 k = 5 MFMA K-steps of 32.
// B (weights) pre-arranged in MFMA fragment order -> loaded direct from global.
#define K_SLOT 10
#define CH_IF 16
#define CH_K 160
#define AST 172            // A_lds row stride in bf16; 86 u32 == 22 mod 32 -> bank period 16
#define NB 128             // nodes per block (kan)
#define NTHR 512

// bucketed CSR build
#define NBUCK 256
#define BSH 9              // bucket = dst>>9, 512 nodes per bucket
#define BUCK_N 512
#define EPT 8
#define EPB 2048           // edges per bin-block

// ws layout (f32 slots)
#define NODES_PAD 100352
#define WF_U16 (8 * 20 * 512)            // 81920 bf16 fragment-ordered weights
#define WG_SLOTS (WF_U16 / 2)            // 40960 f32 slots
#define OFF_DINV 0
#define OFF_ROWPTR (OFF_DINV + NODES_PAD)
#define OFF_ROWEND (OFF_ROWPTR + NODES_PAD)
#define OFF_WT (OFF_ROWEND + NODES_PAD)
#define OFF_BUCK (OFF_WT + WG_SLOTS)     // bc[256] bb[256] bf[256] pad->1024
#define OFF_CSR (OFF_BUCK + 1024)
#define FIXED_SLOTS (OFF_CSR + N_EDGES)
#define AGG_ELEMS (N_NODES * IN_F)

typedef __attribute__((ext_vector_type(8))) short bf16x8;
typedef __attribute__((ext_vector_type(4))) short bf16x4;
typedef __attribute__((ext_vector_type(4))) float f32x4;

__device__ __forceinline__ unsigned int bf16_rne(float v) {
    unsigned int u = __float_as_uint(v);
    u += 0x7FFFu + ((u >> 16) & 1u);
    return u >> 16;
}

// ---- bucketed CSR build ----
__global__ __launch_bounds__(256)
void bucket_count_kernel(const int* __restrict__ dstp, int* __restrict__ bc) {
    __shared__ int lh[NBUCK];
    int t = threadIdx.x;
    lh[t] = 0;
    __syncthreads();
    for (int e = blockIdx.x * 256 + t; e < N_EDGES; e += gridDim.x * 256)
        atomicAdd(&lh[dstp[e] >> BSH], 1);
    __syncthreads();
    if (lh[t]) atomicAdd(&bc[t], lh[t]);
}

__global__ void bucket_scan_kernel(const int* __restrict__ bc, int* __restrict__ bb,
                                   int* __restrict__ bf) {
    __shared__ int sb[NBUCK];
    int t = threadIdx.x;
    int v = bc[t];
    sb[t] = v;
    __syncthreads();
    for (int off = 1; off < NBUCK; off <<= 1) {
        int add = (t >= off) ? sb[t - off] : 0;
        __syncthreads();
        sb[t] += add;
        __syncthreads();
    }
    int excl = sb[t] - v;
    bb[t] = excl;
    bf[t] = excl;
}

__global__ __launch_bounds__(256)
void bucket_bin_kernel(const int* __restrict__ ei, int* __restrict__ bf,
                       int2* __restrict__ pairs) {
    __shared__ int lh[NBUCK];
    __shared__ int lbase[NBUCK];
    int t = threadIdx.x;
    lh[t] = 0;
    __syncthreads();
    int e0 = blockIdx.x * EPB;
    int d[EPT], s[EPT], lp[EPT];
#pragma unroll
    for (int k = 0; k < EPT; ++k) {
        int e = e0 + k * 256 + t;
        bool ok = e < N_EDGES;
        d[k] = ok ? ei[N_EDGES + e] : -1;
        s[k] = ok ? ei[e] : 0;
        lp[k] = ok ? atomicAdd(&lh[d[k] >> BSH], 1) : 0;
    }
    __syncthreads();
    if (lh[t]) lbase[t] = atomicAdd(&bf[t], lh[t]);
    __syncthreads();
#pragma unroll
    for (int k = 0; k < EPT; ++k) {
        if (d[k] >= 0) {
            int b = d[k] >> BSH;
            pairs[lbase[b] + lp[k]] = make_int2(d[k], s[k]);
        }
    }
}

// one block per bucket: local deg hist, scan -> rowptr/rowend/dinv, csr fill (L2-local)
__global__ __launch_bounds__(BUCK_N)
void bucket_build_kernel(const int2* __restrict__ pairs, const int* __restrict__ bc,
                         const int* __restrict__ bb, int* __restrict__ rowptr,
                         int* __restrict__ rowend, float* __restrict__ dinv,
                         int* __restrict__ csr) {
    __shared__ int ldeg[BUCK_N];
    __shared__ int sb[BUCK_N];
    __shared__ int lpos[BUCK_N];
    int t = threadIdx.x;
    int b = blockIdx.x;
    int cnt = bc[b];
    int base = bb[b];
    ldeg[t] = 0;
    __syncthreads();
    for (int j = t; j < cnt; j += BUCK_N) atomicAdd(&ldeg[pairs[base + j].x & (BUCK_N - 1)], 1);
    __syncthreads();
    int v = ldeg[t];
    sb[t] = v;
    __syncthreads();
    for (int off = 1; off < BUCK_N; off <<= 1) {
        int add = (t >= off) ? sb[t - off] : 0;
        __syncthreads();
        sb[t] += add;
        __syncthreads();
    }
    int excl = sb[t] - v;
    int node = (b << BSH) + t;
    if (node < N_NODES) {
        rowptr[node] = base + excl;
        rowend[node] = base + excl + v;
        dinv[node] = (v > 0) ? rsqrtf((float)v) : 0.0f;
    }
    lpos[t] = base + excl;
    __syncthreads();
    for (int j = t; j < cnt; j += BUCK_N) {
        int2 p = pairs[base + j];
        int pos = atomicAdd(&lpos[p.x & (BUCK_N - 1)], 1);
        csr[pos] = p.y;
    }
}

// gather: one wave per dst node, lane = feature
__global__ __launch_bounds__(256)
void gather_kernel(const float* __restrict__ x, const int* __restrict__ csr,
                   const int* __restrict__ rowptr, const int* __restrict__ rowend,
                   const float* __restrict__ dinv, float* __restrict__ agg) {
    int wid = (int)((blockIdx.x * 256 + threadIdx.x) >> 6);
    int lane = threadIdx.x & 63;
    if (wid >= N_NODES) return;
    int start = rowptr[wid];
    int end = rowend[wid];
    float acc = 0.0f;
    int j = start;
    for (; j + 3 < end; j += 4) {
        int s0 = csr[j], s1 = csr[j + 1], s2 = csr[j + 2], s3 = csr[j + 3];
        float a0 = x[s0 * 64 + lane] * dinv[s0];
        float a1 = x[s1 * 64 + lane] * dinv[s1];
        float a2 = x[s2 * 64 + lane] * dinv[s2];
        float a3 = x[s3 * 64 + lane] * dinv[s3];
        acc += a0 + a1 + a2 + a3;
    }
    for (; j < end; ++j) {
        int s = csr[j];
        acc += x[s * 64 + lane] * dinv[s];
    }
    agg[wid * 64 + lane] = acc * dinv[wid];
}

// ---- fallback (ws too small): f32 atomic scatter ----
__global__ void deg_kernel(const int* __restrict__ ei, float* __restrict__ deg) {
    int e = blockIdx.x * blockDim.x + threadIdx.x;
    if (e < N_EDGES) atomicAdd(&deg[ei[N_EDGES + e]], 1.0f);
}
__global__ void dinv_kernel(float* __restrict__ deg) {
    int n = blockIdx.x * blockDim.x + threadIdx.x;
    if (n < N_NODES) {
        float d = deg[n];
        deg[n] = (d > 0.0f) ? rsqrtf(d) : 0.0f;
    }
}
__global__ void scatter_kernel(const float* __restrict__ x, const int* __restrict__ ei,
                               const float* __restrict__ dinv, float* __restrict__ agg) {
    long long gtid = (long long)blockIdx.x * blockDim.x + threadIdx.x;
    int wid = (int)(gtid >> 6);
    int lane = threadIdx.x & 63;
    if (wid >= N_EDGES) return;
    int s = ei[wid];
    int d = ei[N_EDGES + wid];
    float c = dinv[s] * dinv[d];
    atomicAdd(&agg[d * 64 + lane], x[s * 64 + lane] * c);
}

// Wf in MFMA fragment order: Wf[((ch*5+s)*4+t)*512 + lane*8 + j]
//   o = t*16 + (lane&15); kk = (lane>>4)*8 + s*32 + j (0..159)
//   iL = kk/10, c = kk%10, i = (ch&3)*16+iL, path = ch>>2
//   c==8 -> base_w[o][i]; c<8 -> spline_w[o][i][c]; c==9 -> 0
__global__ void wprep_kernel(const float* __restrict__ bwl, const float* __restrict__ swl,
                             const float* __restrict__ bwc, const float* __restrict__ swc,
                             unsigned short* __restrict__ Wf) {
    int gid = blockIdx.x * blockDim.x + threadIdx.x;
    if (gid >= WF_U16) return;
    int fr = gid >> 9;           // ((ch*5+s)*4+t), 0..159
    int lj = gid & 511;
    int lane = lj >> 3, j = lj & 7;
    int ch = fr / 20, r2 = fr - ch * 20;
    int s = r2 >> 2, t = r2 & 3;
    int o = t * 16 + (lane & 15);
    int kk = ((lane >> 4) << 3) + s * 32 + j;   // 0..159
    int iL = kk / K_SLOT, c = kk - iL * K_SLOT;
    int i = (ch & 3) * CH_IF + iL;
    int path = ch >> 2;
    const float* bw = path ? bwc : bwl;
    const float* sw = path ? swc : swl;
    float v = 0.0f;
    if (c == 8) v = bw[o * IN_F + i];
    else if (c < 8) v = sw[o * 512 + i * 8 + c];
    Wf[gid] = (unsigned short)bf16_rne(v);
}

// MFMA KAN v3: 128 nodes/block, 8 waves. x/agg preloaded to regs; B direct
// from global fragment-ordered Wf (L1/L2-resident); A via LDS only (44 KB).
// Safe if agg aliases out: agg is read only in the preload (before any write);
// blocks own disjoint 128-node row ranges.
__global__ __launch_bounds__(NTHR, 4)
void kan_mfma_kernel(const float* __restrict__ x, const float* __restrict__ agg,
                     const unsigned short* __restrict__ Wf, float* __restrict__ out) {
    __shared__ __align__(16) unsigned short A_lds[NB * AST];     // 44032 B

    int tid = threadIdx.x;
    int nbase = blockIdx.x * NB;
    int wid = tid >> 6;
    int lane = tid & 63;

    // ---- preload all feature inputs (4 x-quads + 4 agg-quads per thread)
    int n = tid & (NB - 1);
    int grp = tid >> 7;
    int node = nbase + n;
    bool ok = node < N_NODES;
    const float4 z4 = make_float4(0.f, 0.f, 0.f, 0.f);
    float4 vx[4], va[4];
#pragma unroll
    for (int q = 0; q < 4; ++q)
        vx[q] = ok ? *(const float4*)&x[node * 64 + q * CH_IF + grp * 4] : z4;
#pragma unroll
    for (int q = 0; q < 4; ++q)
        va[q] = ok ? *(const float4*)&agg[node * 64 + q * CH_IF + grp * 4] : z4;

    f32x4 acc[4];
#pragma unroll
    for (int t = 0; t < 4; ++t) acc[t] = (f32x4){0.f, 0.f, 0.f, 0.f};

    int arow = (wid << 4) + (lane & 15);
    int kfrag = (lane >> 4) * 8;
    const unsigned short* Abase = &A_lds[arow * AST + kfrag];
    const bf16x8* Bbase = (const bf16x8*)Wf + lane;

#pragma unroll
    for (int chunk = 0; chunk < 8; ++chunk) {
        const float4 v4 = (chunk < 4) ? vx[chunk] : va[chunk - 4];

        // ---- features: regs -> A_lds (no global access)
        {
            float vv[4] = {v4.x, v4.y, v4.z, v4.w};
            unsigned short* Arow = &A_lds[n * AST];
#pragma unroll
            for (int jj = 0; jj < 4; ++jj) {
                int iL = grp * 4 + jj;
                float v = vv[jj];
                unsigned int* Au = (unsigned int*)(Arow + iL * K_SLOT);
                float sig = __builtin_amdgcn_rcpf(1.0f + __expf(-v));
                Au[0] = 0u; Au[1] = 0u; Au[2] = 0u; Au[3] = 0u;
                Au[4] = bf16_rne(v * sig);
                float s5 = (v + 2.2f) * 2.5f;
                float fm = floorf(s5);
                int m = (int)fm;
                if (m >= 0 && m <= 10) {
                    float t = s5 - fm;
                    float omt = 1.0f - t;
                    float t2 = t * t, t3 = t2 * t;
                    float n0 = omt * omt * omt * (1.0f / 6.0f);
                    float n3 = t3 * (1.0f / 6.0f);
                    float n1 = 0.66666666f - t2 + 0.5f * t3;
                    float n2 = 1.0f - n0 - n1 - n3;
                    unsigned short* As = Arow + iL * K_SLOT;
                    if (m >= 3)           As[m - 3] = (unsigned short)bf16_rne(n0);
                    if (m >= 2 && m <= 9) As[m - 2] = (unsigned short)bf16_rne(n1);
                    if (m >= 1 && m <= 8) As[m - 1] = (unsigned short)bf16_rne(n2);
                    if (m <= 7)           As[m]     = (unsigned short)bf16_rne(n3);
                }
            }
        }
        __syncthreads();

        // ---- MFMA: A from LDS (2x ds_read_b64), B from global Wf (coalesced 16B/lane)
        {
#pragma unroll
            for (int s = 0; s < 5; ++s) {
                bf16x4 alo = *(const bf16x4*)(Abase + s * 32);
                bf16x4 ahi = *(const bf16x4*)(Abase + s * 32 + 4);
                bf16x8 a = __builtin_shufflevector(alo, ahi, 0, 1, 2, 3, 4, 5, 6, 7);
#pragma unroll
                for (int t = 0; t < 4; ++t) {
                    bf16x8 b = Bbase[((chunk * 5 + s) * 4 + t) * 64];
                    acc[t] = __builtin_amdgcn_mfma_f32_16x16x32_bf16(a, b, acc[t], 0, 0, 0);
                }
            }
        }
        __syncthreads();
    }

    // ---- epilogue: C/D layout col=lane&15, row=(lane>>4)*4+reg
#pragma unroll
    for (int t = 0; t < 4; ++t) {
#pragma unroll
        for (int r = 0; r < 4; ++r) {
            int nd = nbase + (wid << 4) + (lane >> 4) * 4 + r;
            if (nd < N_NODES) out[nd * 64 + t * 16 + (lane & 15)] = acc[t][r];
        }
    }
}

extern "C" void kernel_launch(void* const* d_in, const int* in_sizes, int n_in,
                              void* d_out, int out_size, void* d_ws, size_t ws_size,
                              hipStream_t stream) {
    const float* x   = (const float*)d_in[0];
    const float* bwl = (const float*)d_in[1];
    const float* swl = (const float*)d_in[2];
    const float* bwc = (const float*)d_in[3];
    const float* swc = (const float*)d_in[4];
    const int*   ei  = (const int*)d_in[5];
    float* out = (float*)d_out;

    float* ws = (float*)d_ws;
    float* dinv = ws + OFF_DINV;
    int* rowptr = (int*)(ws + OFF_ROWPTR);
    int* rowend = (int*)(ws + OFF_ROWEND);
    unsigned short* Wf = (unsigned short*)(ws + OFF_WT);
    int* bc = (int*)(ws + OFF_BUCK);
    int* bb = bc + NBUCK;
    int* bf = bb + NBUCK;
    int* csr = (int*)(ws + OFF_CSR);

    const bool has_csr = ws_size >= (size_t)FIXED_SLOTS * sizeof(float);
    const bool agg_in_ws = ws_size >= ((size_t)FIXED_SLOTS + AGG_ELEMS) * sizeof(float);
    float* agg = (has_csr && agg_in_ws) ? (ws + FIXED_SLOTS) : out;
    int2* pairs = (int2*)agg;   // overlay: pairs dead before gather writes agg

    if (has_csr) {
        hipMemsetAsync(bc, 0, NBUCK * sizeof(int), stream);
        bucket_count_kernel<<<1024, 256, 0, stream>>>(ei + N_EDGES, bc);
        bucket_scan_kernel<<<1, NBUCK, 0, stream>>>(bc, bb, bf);
        bucket_bin_kernel<<<(N_EDGES + EPB - 1) / EPB, 256, 0, stream>>>(ei, bf, pairs);
        bucket_build_kernel<<<NBUCK, BUCK_N, 0, stream>>>(pairs, bc, bb, rowptr, rowend, dinv, csr);
        gather_kernel<<<(N_NODES * 64 + 255) / 256, 256, 0, stream>>>(x, csr, rowptr, rowend, dinv, agg);
    } else {
        float* deg = dinv;
        hipMemsetAsync(deg, 0, (size_t)NODES_PAD * sizeof(float), stream);
        deg_kernel<<<(N_EDGES + 255) / 256, 256, 0, stream>>>(ei, deg);
        dinv_kernel<<<(N_NODES + 255) / 256, 256, 0, stream>>>(deg);
        hipMemsetAsync(agg, 0, (size_t)AGG_ELEMS * sizeof(float), stream);
        long long scatter_threads = (long long)N_EDGES * 64;
        int scatter_blocks = (int)((scatter_threads + 255) / 256);
        scatter_kernel<<<scatter_blocks, 256, 0, stream>>>(x, ei, deg, agg);
    }

    wprep_kernel<<<(WF_U16 + 255) / 256, 256, 0, stream>>>(bwl, swl, bwc, swc, Wf);

    kan_mfma_kernel<<<(N_NODES + NB - 1) / NB, NTHR, 0, stream>>>(x, agg, Wf, out);
}

// Round 14
// 216.608 us; speedup vs baseline: 4.5893x; 1.0555x over previous
//
#include <hip/hip_runtime.h>
#include <math.h>

#define N_NODES 100000
#define N_EDGES 1600000
#define IN_F 64
#define OUT_F 64

// KAN GEMM K layout: k = (path*64 + i)*10 + c; c=0..7 spline bases, c=8 silu,
// c=9 zero pad. K'=1280. Chunk = 16 in-feats = 160 k = 5 MFMA K-steps of 32.
// B (weights) pre-arranged in MFMA fragment order -> loaded direct from global.
#define K_SLOT 10
#define CH_IF 16
#define CH_K 160
#define AST 172            // A_lds row stride in bf16; 86 u32 == 22 mod 32 -> bank period 16
#define NB 64              // nodes per block (kan): small tile -> ~7 blocks/CU resident
#define NTHR 256

// bucketed CSR build
#define NBUCK 256
#define BSH 9              // bucket = dst>>9, 512 nodes per bucket
#define BUCK_N 512
#define EPT 8
#define EPB 2048           // edges per bin-block

// ws layout (f32 slots)
#define NODES_PAD 100352
#define WF_U16 (8 * 20 * 512)            // 81920 bf16 fragment-ordered weights
#define WG_SLOTS (WF_U16 / 2)            // 40960 f32 slots
#define OFF_DINV 0
#define OFF_ROWPTR (OFF_DINV + NODES_PAD)
#define OFF_ROWEND (OFF_ROWPTR + NODES_PAD)
#define OFF_WT (OFF_ROWEND + NODES_PAD)
#define OFF_BUCK (OFF_WT + WG_SLOTS)     // bc[256] bb[256] bf[256] pad->1024
#define OFF_CSR (OFF_BUCK + 1024)
#define FIXED_SLOTS (OFF_CSR + N_EDGES)
#define AGG_ELEMS (N_NODES * IN_F)

typedef __attribute__((ext_vector_type(8))) short bf16x8;
typedef __attribute__((ext_vector_type(4))) short bf16x4;
typedef __attribute__((ext_vector_type(4))) float f32x4;

__device__ __forceinline__ unsigned int bf16_rne(float v) {
    unsigned int u = __float_as_uint(v);
    u += 0x7FFFu + ((u >> 16) & 1u);
    return u >> 16;
}

// ---- bucketed CSR build ----
__global__ __launch_bounds__(256)
void bucket_count_kernel(const int* __restrict__ dstp, int* __restrict__ bc) {
    __shared__ int lh[NBUCK];
    int t = threadIdx.x;
    lh[t] = 0;
    __syncthreads();
    for (int e = blockIdx.x * 256 + t; e < N_EDGES; e += gridDim.x * 256)
        atomicAdd(&lh[dstp[e] >> BSH], 1);
    __syncthreads();
    if (lh[t]) atomicAdd(&bc[t], lh[t]);
}

__global__ void bucket_scan_kernel(const int* __restrict__ bc, int* __restrict__ bb,
                                   int* __restrict__ bf) {
    __shared__ int sb[NBUCK];
    int t = threadIdx.x;
    int v = bc[t];
    sb[t] = v;
    __syncthreads();
    for (int off = 1; off < NBUCK; off <<= 1) {
        int add = (t >= off) ? sb[t - off] : 0;
        __syncthreads();
        sb[t] += add;
        __syncthreads();
    }
    int excl = sb[t] - v;
    bb[t] = excl;
    bf[t] = excl;
}

__global__ __launch_bounds__(256)
void bucket_bin_kernel(const int* __restrict__ ei, int* __restrict__ bf,
                       int2* __restrict__ pairs) {
    __shared__ int lh[NBUCK];
    __shared__ int lbase[NBUCK];
    int t = threadIdx.x;
    lh[t] = 0;
    __syncthreads();
    int e0 = blockIdx.x * EPB;
    int d[EPT], s[EPT], lp[EPT];
#pragma unroll
    for (int k = 0; k < EPT; ++k) {
        int e = e0 + k * 256 + t;
        bool ok = e < N_EDGES;
        d[k] = ok ? ei[N_EDGES + e] : -1;
        s[k] = ok ? ei[e] : 0;
        lp[k] = ok ? atomicAdd(&lh[d[k] >> BSH], 1) : 0;
    }
    __syncthreads();
    if (lh[t]) lbase[t] = atomicAdd(&bf[t], lh[t]);
    __syncthreads();
#pragma unroll
    for (int k = 0; k < EPT; ++k) {
        if (d[k] >= 0) {
            int b = d[k] >> BSH;
            pairs[lbase[b] + lp[k]] = make_int2(d[k], s[k]);
        }
    }
}

// one block per bucket: local deg hist, scan -> rowptr/rowend/dinv, csr fill (L2-local)
__global__ __launch_bounds__(BUCK_N)
void bucket_build_kernel(const int2* __restrict__ pairs, const int* __restrict__ bc,
                         const int* __restrict__ bb, int* __restrict__ rowptr,
                         int* __restrict__ rowend, float* __restrict__ dinv,
                         int* __restrict__ csr) {
    __shared__ int ldeg[BUCK_N];
    __shared__ int sb[BUCK_N];
    __shared__ int lpos[BUCK_N];
    int t = threadIdx.x;
    int b = blockIdx.x;
    int cnt = bc[b];
    int base = bb[b];
    ldeg[t] = 0;
    __syncthreads();
    for (int j = t; j < cnt; j += BUCK_N) atomicAdd(&ldeg[pairs[base + j].x & (BUCK_N - 1)], 1);
    __syncthreads();
    int v = ldeg[t];
    sb[t] = v;
    __syncthreads();
    for (int off = 1; off < BUCK_N; off <<= 1) {
        int add = (t >= off) ? sb[t - off] : 0;
        __syncthreads();
        sb[t] += add;
        __syncthreads();
    }
    int excl = sb[t] - v;
    int node = (b << BSH) + t;
    if (node < N_NODES) {
        rowptr[node] = base + excl;
        rowend[node] = base + excl + v;
        dinv[node] = (v > 0) ? rsqrtf((float)v) : 0.0f;
    }
    lpos[t] = base + excl;
    __syncthreads();
    for (int j = t; j < cnt; j += BUCK_N) {
        int2 p = pairs[base + j];
        int pos = atomicAdd(&lpos[p.x & (BUCK_N - 1)], 1);
        csr[pos] = p.y;
    }
}

// gather: one wave per dst node, lane = feature
__global__ __launch_bounds__(256)
void gather_kernel(const float* __restrict__ x, const int* __restrict__ csr,
                   const int* __restrict__ rowptr, const int* __restrict__ rowend,
                   const float* __restrict__ dinv, float* __restrict__ agg) {
    int wid = (int)((blockIdx.x * 256 + threadIdx.x) >> 6);
    int lane = threadIdx.x & 63;
    if (wid >= N_NODES) return;
    int start = rowptr[wid];
    int end = rowend[wid];
    float acc = 0.0f;
    int j = start;
    for (; j + 3 < end; j += 4) {
        int s0 = csr[j], s1 = csr[j + 1], s2 = csr[j + 2], s3 = csr[j + 3];
        float a0 = x[s0 * 64 + lane] * dinv[s0];
        float a1 = x[s1 * 64 + lane] * dinv[s1];
        float a2 = x[s2 * 64 + lane] * dinv[s2];
        float a3 = x[s3 * 64 + lane] * dinv[s3];
        acc += a0 + a1 + a2 + a3;
    }
    for (; j < end; ++j) {
        int s = csr[j];
        acc += x[s * 64 + lane] * dinv[s];
    }
    agg[wid * 64 + lane] = acc * dinv[wid];
}

// ---- fallback (ws too small): f32 atomic scatter ----
__global__ void deg_kernel(const int* __restrict__ ei, float* __restrict__ deg) {
    int e = blockIdx.x * blockDim.x + threadIdx.x;
    if (e < N_EDGES) atomicAdd(&deg[ei[N_EDGES + e]], 1.0f);
}
__global__ void dinv_kernel(float* __restrict__ deg) {
    int n = blockIdx.x * blockDim.x + threadIdx.x;
    if (n < N_NODES) {
        float d = deg[n];
        deg[n] = (d > 0.0f) ? rsqrtf(d) : 0.0f;
    }
}
__global__ void scatter_kernel(const float* __restrict__ x, const int* __restrict__ ei,
                               const float* __restrict__ dinv, float* __restrict__ agg) {
    long long gtid = (long long)blockIdx.x * blockDim.x + threadIdx.x;
    int wid = (int)(gtid >> 6);
    int lane = threadIdx.x & 63;
    if (wid >= N_EDGES) return;
    int s = ei[wid];
    int d = ei[N_EDGES + wid];
    float c = dinv[s] * dinv[d];
    atomicAdd(&agg[d * 64 + lane], x[s * 64 + lane] * c);
}

// Wf in MFMA fragment order: Wf[((ch*5+s)*4+t)*512 + lane*8 + j]
//   o = t*16 + (lane&15); kk = (lane>>4)*8 + s*32 + j (0..159)
//   iL = kk/10, c = kk%10, i = (ch&3)*16+iL, path = ch>>2
//   c==8 -> base_w[o][i]; c<8 -> spline_w[o][i][c]; c==9 -> 0
__global__ void wprep_kernel(const float* __restrict__ bwl, const float* __restrict__ swl,
                             const float* __restrict__ bwc, const float* __restrict__ swc,
                             unsigned short* __restrict__ Wf) {
    int gid = blockIdx.x * blockDim.x + threadIdx.x;
    if (gid >= WF_U16) return;
    int fr = gid >> 9;           // ((ch*5+s)*4+t), 0..159
    int lj = gid & 511;
    int lane = lj >> 3, j = lj & 7;
    int ch = fr / 20, r2 = fr - ch * 20;
    int s = r2 >> 2, t = r2 & 3;
    int o = t * 16 + (lane & 15);
    int kk = ((lane >> 4) << 3) + s * 32 + j;   // 0..159
    int iL = kk / K_SLOT, c = kk - iL * K_SLOT;
    int i = (ch & 3) * CH_IF + iL;
    int path = ch >> 2;
    const float* bw = path ? bwc : bwl;
    const float* sw = path ? swc : swl;
    float v = 0.0f;
    if (c == 8) v = bw[o * IN_F + i];
    else if (c < 8) v = sw[o * 512 + i * 8 + c];
    Wf[gid] = (unsigned short)bf16_rne(v);
}

// MFMA KAN v4: 64 nodes/block, 4 waves, 21.5 KB LDS -> ~7 blocks/CU resident.
// x/agg preloaded to regs; B direct from global fragment-ordered Wf; A via LDS.
// Wave w computes in-feat quarter w (grp==wid) for all 64 nodes.
// Safe if agg aliases out: agg is read only in the preload (before any write);
// blocks own disjoint 64-node row ranges.
__global__ __launch_bounds__(NTHR, 8)
void kan_mfma_kernel(const float* __restrict__ x, const float* __restrict__ agg,
                     const unsigned short* __restrict__ Wf, float* __restrict__ out) {
    __shared__ __align__(16) unsigned short A_lds[NB * AST];     // 22016 B

    int tid = threadIdx.x;
    int nbase = blockIdx.x * NB;
    int wid = tid >> 6;
    int lane = tid & 63;

    // ---- preload all feature inputs (4 x-quads + 4 agg-quads per thread)
    int n = tid & (NB - 1);          // = lane
    int grp = tid >> 6;              // = wid
    int node = nbase + n;
    bool ok = node < N_NODES;
    const float4 z4 = make_float4(0.f, 0.f, 0.f, 0.f);
    float4 vx[4], va[4];
#pragma unroll
    for (int q = 0; q < 4; ++q)
        vx[q] = ok ? *(const float4*)&x[node * 64 + q * CH_IF + grp * 4] : z4;
#pragma unroll
    for (int q = 0; q < 4; ++q)
        va[q] = ok ? *(const float4*)&agg[node * 64 + q * CH_IF + grp * 4] : z4;

    f32x4 acc[4];
#pragma unroll
    for (int t = 0; t < 4; ++t) acc[t] = (f32x4){0.f, 0.f, 0.f, 0.f};

    int arow = (wid << 4) + (lane & 15);
    int kfrag = (lane >> 4) * 8;
    const unsigned short* Abase = &A_lds[arow * AST + kfrag];
    const bf16x8* Bbase = (const bf16x8*)Wf + lane;

#pragma unroll
    for (int chunk = 0; chunk < 8; ++chunk) {
        const float4 v4 = (chunk < 4) ? vx[chunk] : va[chunk - 4];

        // ---- features: regs -> A_lds (no global access)
        {
            float vv[4] = {v4.x, v4.y, v4.z, v4.w};
            unsigned short* Arow = &A_lds[n * AST];
#pragma unroll
            for (int jj = 0; jj < 4; ++jj) {
                int iL = grp * 4 + jj;
                float v = vv[jj];
                unsigned int* Au = (unsigned int*)(Arow + iL * K_SLOT);
                float sig = __builtin_amdgcn_rcpf(1.0f + __expf(-v));
                Au[0] = 0u; Au[1] = 0u; Au[2] = 0u; Au[3] = 0u;
                Au[4] = bf16_rne(v * sig);
                float s5 = (v + 2.2f) * 2.5f;
                float fm = floorf(s5);
                int m = (int)fm;
                if (m >= 0 && m <= 10) {
                    float t = s5 - fm;
                    float omt = 1.0f - t;
                    float t2 = t * t, t3 = t2 * t;
                    float n0 = omt * omt * omt * (1.0f / 6.0f);
                    float n3 = t3 * (1.0f / 6.0f);
                    float n1 = 0.66666666f - t2 + 0.5f * t3;
                    float n2 = 1.0f - n0 - n1 - n3;
                    unsigned short* As = Arow + iL * K_SLOT;
                    if (m >= 3)           As[m - 3] = (unsigned short)bf16_rne(n0);
                    if (m >= 2 && m <= 9) As[m - 2] = (unsigned short)bf16_rne(n1);
                    if (m >= 1 && m <= 8) As[m - 1] = (unsigned short)bf16_rne(n2);
                    if (m <= 7)           As[m]     = (unsigned short)bf16_rne(n3);
                }
            }
        }
        __syncthreads();

        // ---- MFMA: A from LDS (2x ds_read_b64), B from global Wf (coalesced 16B/lane)
        {
#pragma unroll
            for (int s = 0; s < 5; ++s) {
                bf16x4 alo = *(const bf16x4*)(Abase + s * 32);
                bf16x4 ahi = *(const bf16x4*)(Abase + s * 32 + 4);
                bf16x8 a = __builtin_shufflevector(alo, ahi, 0, 1, 2, 3, 4, 5, 6, 7);
#pragma unroll
                for (int t = 0; t < 4; ++t) {
                    bf16x8 b = Bbase[((chunk * 5 + s) * 4 + t) * 64];
                    acc[t] = __builtin_amdgcn_mfma_f32_16x16x32_bf16(a, b, acc[t], 0, 0, 0);
                }
            }
        }
        __syncthreads();
    }

    // ---- epilogue: C/D layout col=lane&15, row=(lane>>4)*4+reg
#pragma unroll
    for (int t = 0; t < 4; ++t) {
#pragma unroll
        for (int r = 0; r < 4; ++r) {
            int nd = nbase + (wid << 4) + (lane >> 4) * 4 + r;
            if (nd < N_NODES) out[nd * 64 + t * 16 + (lane & 15)] = acc[t][r];
        }
    }
}

extern "C" void kernel_launch(void* const* d_in, const int* in_sizes, int n_in,
                              void* d_out, int out_size, void* d_ws, size_t ws_size,
                              hipStream_t stream) {
    const float* x   = (const float*)d_in[0];
    const float* bwl = (const float*)d_in[1];
    const float* swl = (const float*)d_in[2];
    const float* bwc = (const float*)d_in[3];
    const float* swc = (const float*)d_in[4];
    const int*   ei  = (const int*)d_in[5];
    float* out = (float*)d_out;

    float* ws = (float*)d_ws;
    float* dinv = ws + OFF_DINV;
    int* rowptr = (int*)(ws + OFF_ROWPTR);
    int* rowend = (int*)(ws + OFF_ROWEND);
    unsigned short* Wf = (unsigned short*)(ws + OFF_WT);
    int* bc = (int*)(ws + OFF_BUCK);
    int* bb = bc + NBUCK;
    int* bf = bb + NBUCK;
    int* csr = (int*)(ws + OFF_CSR);

    const bool has_csr = ws_size >= (size_t)FIXED_SLOTS * sizeof(float);
    const bool agg_in_ws = ws_size >= ((size_t)FIXED_SLOTS + AGG_ELEMS) * sizeof(float);
    float* agg = (has_csr && agg_in_ws) ? (ws + FIXED_SLOTS) : out;
    int2* pairs = (int2*)agg;   // overlay: pairs dead before gather writes agg

    if (has_csr) {
        hipMemsetAsync(bc, 0, NBUCK * sizeof(int), stream);
        bucket_count_kernel<<<1024, 256, 0, stream>>>(ei + N_EDGES, bc);
        bucket_scan_kernel<<<1, NBUCK, 0, stream>>>(bc, bb, bf);
        bucket_bin_kernel<<<(N_EDGES + EPB - 1) / EPB, 256, 0, stream>>>(ei, bf, pairs);
        bucket_build_kernel<<<NBUCK, BUCK_N, 0, stream>>>(pairs, bc, bb, rowptr, rowend, dinv, csr);
        gather_kernel<<<(N_NODES * 64 + 255) / 256, 256, 0, stream>>>(x, csr, rowptr, rowend, dinv, agg);
    } else {
        float* deg = dinv;
        hipMemsetAsync(deg, 0, (size_t)NODES_PAD * sizeof(float), stream);
        deg_kernel<<<(N_EDGES + 255) / 256, 256, 0, stream>>>(ei, deg);
        dinv_kernel<<<(N_NODES + 255) / 256, 256, 0, stream>>>(deg);
        hipMemsetAsync(agg, 0, (size_t)AGG_ELEMS * sizeof(float), stream);
        long long scatter_threads = (long long)N_EDGES * 64;
        int scatter_blocks = (int)((scatter_threads + 255) / 256);
        scatter_kernel<<<scatter_blocks, 256, 0, stream>>>(x, ei, deg, agg);
    }

    wprep_kernel<<<(WF_U16 + 255) / 256, 256, 0, stream>>>(bwl, swl, bwc, swc, Wf);

    kan_mfma_kernel<<<(N_NODES + NB - 1) / NB, NTHR, 0, stream>>>(x, agg, Wf, out);
}